// Round 1
// baseline (5604.041 us; speedup 1.0000x reference)
//
#include <hip/hip_runtime.h>
#include <stdint.h>

#define Bz 256
#define Tz 128
#define DWz 768
#define DHz 768
#define G4z 3072

typedef __attribute__((ext_vector_type(8))) short short8;
typedef __attribute__((ext_vector_type(4))) float f32x4;

__device__ __forceinline__ unsigned short f2bf(float x) {
    union { float f; unsigned int u; } v; v.f = x;
    unsigned int u = v.u;
    return (unsigned short)((u + 0x7fffu + ((u >> 16) & 1u)) >> 16);
}
__device__ __forceinline__ float bf2f(unsigned short h) {
    union { unsigned int u; float f; } v; v.u = ((unsigned int)h) << 16;
    return v.f;
}
__device__ __forceinline__ float sigm(float x) { return 1.0f / (1.0f + expf(-x)); }
// swizzled transposed-B LDS offset: row stride 40 (16B-aligned), k-group xor to break
// the 16-lane same-bank pattern in the transpose writes (4-way residual, ~1.6x only)
__device__ __forceinline__ int sboff(int n, int k) {
    return n * 40 + ((((k >> 3) ^ ((n >> 3) & 3))) << 3) + (k & 7);
}

// ---------- fp32 -> bf16 bulk convert ----------
__global__ void k_cvt4(const float* __restrict__ src, unsigned short* __restrict__ dst, int n4) {
    int i = blockIdx.x * blockDim.x + threadIdx.x;
    int st = gridDim.x * blockDim.x;
    for (; i < n4; i += st) {
        float4 v = ((const float4*)src)[i];
        ushort4 o;
        o.x = f2bf(v.x); o.y = f2bf(v.y); o.z = f2bf(v.z); o.w = f2bf(v.w);
        ((ushort4*)dst)[i] = o;
    }
}

// ---------- gather aspect embedding ----------
__global__ void k_prep_tx(const int* __restrict__ target, const float* __restrict__ temb,
                          float* __restrict__ tx) {
    int b = blockIdx.x;
    long row = (long)target[b] * DWz;
    for (int d = threadIdx.x; d < DWz; d += blockDim.x)
        tx[b * DWz + d] = temb[row + d];
}

// ---------- generic fp32 tiled GEMM with bias (for const_gates) ----------
__global__ void k_gemm_f32_bias(const float* __restrict__ A, const float* __restrict__ Bm,
                                const float* __restrict__ bias, float* __restrict__ C,
                                int M, int N, int K, int lda, int ldb) {
    __shared__ float sA[16][65];
    __shared__ float sB[16][65];
    int bn = blockIdx.x * 64, bm = blockIdx.y * 64;
    int tx = threadIdx.x & 15, ty = threadIdx.x >> 4;
    float acc[4][4] = {};
    for (int k0 = 0; k0 < K; k0 += 16) {
        for (int l = threadIdx.x; l < 64 * 16; l += 256) {
            int m = l >> 4, k = l & 15;
            sA[k][m] = A[(long)(bm + m) * lda + k0 + k];
        }
        for (int l = threadIdx.x; l < 16 * 64; l += 256) {
            int k = l >> 6, n = l & 63;
            sB[k][n] = Bm[(long)(k0 + k) * ldb + bn + n];
        }
        __syncthreads();
        for (int k = 0; k < 16; ++k) {
            float a0[4], b0[4];
#pragma unroll
            for (int i = 0; i < 4; ++i) a0[i] = sA[k][ty * 4 + i];
#pragma unroll
            for (int j = 0; j < 4; ++j) b0[j] = sB[k][tx * 4 + j];
#pragma unroll
            for (int i = 0; i < 4; ++i)
#pragma unroll
                for (int j = 0; j < 4; ++j) acc[i][j] += a0[i] * b0[j];
        }
        __syncthreads();
    }
#pragma unroll
    for (int i = 0; i < 4; ++i)
#pragma unroll
        for (int j = 0; j < 4; ++j) {
            int m = bm + ty * 4 + i, n = bn + tx * 4 + j;
            C[(long)m * N + n] = acc[i][j] + bias[n];
        }
}

// ---------- xW = emb[sent] @ W_ih[:768]  (bf16 MFMA, row m' = t*256+b) ----------
__global__ __launch_bounds__(256) void k_gemm_x(const float* __restrict__ emb,
                                                const int* __restrict__ sent,
                                                const unsigned short* __restrict__ Wb,
                                                unsigned short* __restrict__ xW) {
    __shared__ unsigned short sA[128 * 40];
    __shared__ unsigned short sB[128 * 40];
    int tid = threadIdx.x;
    int n0 = blockIdx.x * 128;
    int m0 = blockIdx.y * 128;
    int wid = tid >> 6, lane = tid & 63, l15 = lane & 15, q = lane >> 4;
    int wm = wid >> 1, wn = wid & 1;

    int arow = tid >> 1;
    int kp = (tid & 1) * 16;
    int m = m0 + arow;
    int tt = m >> 8;      // m / 256  -> time
    int bb = m & 255;     // batch
    long gbase = (long)sent[bb * Tz + tt] * DWz;

    f32x4 acc[4][4];
    f32x4 zz = {0.f, 0.f, 0.f, 0.f};
#pragma unroll
    for (int i = 0; i < 4; ++i)
#pragma unroll
        for (int j = 0; j < 4; ++j) acc[i][j] = zz;

    for (int k0 = 0; k0 < DWz; k0 += 32) {
        {   // A: gather + convert fp32 -> bf16
            const float* src = emb + gbase + k0 + kp;
            alignas(16) unsigned short tmp[16];
#pragma unroll
            for (int it = 0; it < 4; ++it) {
                float4 v = ((const float4*)src)[it];
                tmp[it * 4 + 0] = f2bf(v.x); tmp[it * 4 + 1] = f2bf(v.y);
                tmp[it * 4 + 2] = f2bf(v.z); tmp[it * 4 + 3] = f2bf(v.w);
            }
            *(int4*)(sA + arow * 40 + kp) = *(const int4*)tmp;
            *(int4*)(sA + arow * 40 + kp + 8) = *(const int4*)(tmp + 8);
        }
#pragma unroll
        for (int it = 0; it < 2; ++it) {   // B: transpose into LDS (swizzled)
            int s = tid + it * 256;
            int k = s >> 4;
            int n = (s & 15) * 8;
            int4 v = *(const int4*)(Wb + (long)(k0 + k) * G4z + n0 + n);
            const unsigned short* pv = (const unsigned short*)&v;
#pragma unroll
            for (int e = 0; e < 8; ++e) sB[sboff(n + e, k)] = pv[e];
        }
        __syncthreads();
        short8 af[4], bfr[4];
#pragma unroll
        for (int i = 0; i < 4; ++i)
            af[i] = *(const short8*)(sA + (wm * 64 + i * 16 + l15) * 40 + q * 8);
#pragma unroll
        for (int j = 0; j < 4; ++j) {
            int n = wn * 64 + j * 16 + l15;
            bfr[j] = *(const short8*)(sB + n * 40 + ((q ^ ((n >> 3) & 3)) << 3));
        }
#pragma unroll
        for (int i = 0; i < 4; ++i)
#pragma unroll
            for (int j = 0; j < 4; ++j)
                acc[i][j] = __builtin_amdgcn_mfma_f32_16x16x32_bf16(af[i], bfr[j], acc[i][j], 0, 0, 0);
        __syncthreads();
    }
#pragma unroll
    for (int i = 0; i < 4; ++i) {
        int row = m0 + wm * 64 + i * 16 + q * 4;
#pragma unroll
        for (int j = 0; j < 4; ++j) {
            int col = n0 + wn * 64 + j * 16 + l15;
#pragma unroll
            for (int r = 0; r < 4; ++r)
                xW[(long)(row + r) * G4z + col] = f2bf(acc[i][j][r]);
        }
    }
}

// ---------- one LSTM time step: gates = xW[t] + const_gates + h@W_hh, fused pointwise ----------
__global__ __launch_bounds__(256) void k_lstm_step(int t, const unsigned short* __restrict__ xW,
                                                   const float* __restrict__ constg,
                                                   const unsigned short* __restrict__ Whh,
                                                   unsigned short* __restrict__ Hbf,
                                                   float* __restrict__ cbuf,
                                                   const int* __restrict__ lens) {
    __shared__ unsigned short sA[128 * 40];
    __shared__ unsigned short sB[128 * 40];
    __shared__ float sG[128 * 132];
    int tid = threadIdx.x;
    int bm = blockIdx.x & 1;            // 128-batch tile
    int d0 = (blockIdx.x >> 1) * 32;    // hidden-dim slab; cols {g*768+d0..+32} for g=0..3
    int wid = tid >> 6, lane = tid & 63, l15 = lane & 15, q = lane >> 4;
    int wm = wid >> 1, wn = wid & 1;

    f32x4 acc[4][4];
#pragma unroll
    for (int i = 0; i < 4; ++i) {
        int row = bm * 128 + wm * 64 + i * 16 + q * 4;
#pragma unroll
        for (int j = 0; j < 4; ++j) {
            int nl = wn * 64 + j * 16 + l15;
            int n = (nl >> 5) * DHz + d0 + (nl & 31);
#pragma unroll
            for (int r = 0; r < 4; ++r) {
                int b = row + r;
                acc[i][j][r] = bf2f(xW[((long)t * 256 + b) * G4z + n]) + constg[(long)b * G4z + n];
            }
        }
    }

    int arow = tid >> 1;
    int kp = (tid & 1) * 16;
    int ab = bm * 128 + arow;
    const unsigned short* hsrc = Hbf + ((long)ab * Tz + (t - 1)) * DHz;

    for (int k0 = 0; k0 < DHz; k0 += 32) {
        if (t > 0) {
            *(int4*)(sA + arow * 40 + kp) = *(const int4*)(hsrc + k0 + kp);
            *(int4*)(sA + arow * 40 + kp + 8) = *(const int4*)(hsrc + k0 + kp + 8);
        } else {
            int4 z; z.x = 0; z.y = 0; z.z = 0; z.w = 0;
            *(int4*)(sA + arow * 40 + kp) = z;
            *(int4*)(sA + arow * 40 + kp + 8) = z;
        }
#pragma unroll
        for (int it = 0; it < 2; ++it) {
            int s = tid + it * 256;
            int k = s >> 4;
            int sub = s & 15;
            int g = sub >> 2, qq = sub & 3;
            int nl = g * 32 + qq * 8;
            int n = g * DHz + d0 + qq * 8;
            int4 v = *(const int4*)(Whh + (long)(k0 + k) * G4z + n);
            const unsigned short* pv = (const unsigned short*)&v;
#pragma unroll
            for (int e = 0; e < 8; ++e) sB[sboff(nl + e, k)] = pv[e];
        }
        __syncthreads();
        short8 af[4], bfr[4];
#pragma unroll
        for (int i = 0; i < 4; ++i)
            af[i] = *(const short8*)(sA + (wm * 64 + i * 16 + l15) * 40 + q * 8);
#pragma unroll
        for (int j = 0; j < 4; ++j) {
            int n = wn * 64 + j * 16 + l15;
            bfr[j] = *(const short8*)(sB + n * 40 + ((q ^ ((n >> 3) & 3)) << 3));
        }
#pragma unroll
        for (int i = 0; i < 4; ++i)
#pragma unroll
            for (int j = 0; j < 4; ++j)
                acc[i][j] = __builtin_amdgcn_mfma_f32_16x16x32_bf16(af[i], bfr[j], acc[i][j], 0, 0, 0);
        __syncthreads();
    }
    // spill gates to LDS for cross-wave gather of (i,f,g,o)
#pragma unroll
    for (int i = 0; i < 4; ++i) {
        int rr = wm * 64 + i * 16 + q * 4;
#pragma unroll
        for (int j = 0; j < 4; ++j) {
            int nl = wn * 64 + j * 16 + l15;
#pragma unroll
            for (int r = 0; r < 4; ++r) sG[(rr + r) * 132 + nl] = acc[i][j][r];
        }
    }
    __syncthreads();
#pragma unroll
    for (int e = 0; e < 16; ++e) {
        int idx = tid + e * 256;
        int rr = idx >> 5;
        int dc = idx & 31;
        int b = bm * 128 + rr;
        int d = d0 + dc;
        float gi = sG[rr * 132 + dc];
        float gf = sG[rr * 132 + 32 + dc];
        float gg = sG[rr * 132 + 64 + dc];
        float go = sG[rr * 132 + 96 + dc];
        float cold = cbuf[(long)b * DHz + d];
        float cn = sigm(gf) * cold + sigm(gi) * tanhf(gg);
        float hn = sigm(go) * tanhf(cn);
        bool upd = t < lens[b];
        float hold = (t > 0) ? bf2f(Hbf[((long)b * Tz + t - 1) * DHz + d]) : 0.0f;
        float h = upd ? hn : hold;
        cbuf[(long)b * DHz + d] = upd ? cn : cold;
        Hbf[((long)b * Tz + t) * DHz + d] = f2bf(h);
    }
}

// ---------- scores[b,t] = sum_d w[d]*tanh( (H@Wh)[b,t,d] )  (Wv/w[768:] cancel in softmax) ----------
__global__ __launch_bounds__(256) void k_scores(const unsigned short* __restrict__ Hbf,
                                                const unsigned short* __restrict__ Whb,
                                                const float* __restrict__ wv,
                                                float* __restrict__ scores) {
    __shared__ unsigned short sA[128 * 40];
    __shared__ unsigned short sB[128 * 40];
    __shared__ float sred[128];
    int tid = threadIdx.x;
    int n0 = blockIdx.x * 128;
    int m0 = blockIdx.y * 128;
    int wid = tid >> 6, lane = tid & 63, l15 = lane & 15, q = lane >> 4;
    int wm = wid >> 1, wn = wid & 1;

    f32x4 acc[4][4];
    f32x4 zz = {0.f, 0.f, 0.f, 0.f};
#pragma unroll
    for (int i = 0; i < 4; ++i)
#pragma unroll
        for (int j = 0; j < 4; ++j) acc[i][j] = zz;

    int arow = tid >> 1;
    int kp = (tid & 1) * 16;
    const unsigned short* asrc = Hbf + (long)(m0 + arow) * DHz;

    for (int k0 = 0; k0 < DHz; k0 += 32) {
        *(int4*)(sA + arow * 40 + kp) = *(const int4*)(asrc + k0 + kp);
        *(int4*)(sA + arow * 40 + kp + 8) = *(const int4*)(asrc + k0 + kp + 8);
#pragma unroll
        for (int it = 0; it < 2; ++it) {
            int s = tid + it * 256;
            int k = s >> 4;
            int n = (s & 15) * 8;
            int4 v = *(const int4*)(Whb + (long)(k0 + k) * DHz + n0 + n);
            const unsigned short* pv = (const unsigned short*)&v;
#pragma unroll
            for (int e = 0; e < 8; ++e) sB[sboff(n + e, k)] = pv[e];
        }
        __syncthreads();
        short8 af[4], bfr[4];
#pragma unroll
        for (int i = 0; i < 4; ++i)
            af[i] = *(const short8*)(sA + (wm * 64 + i * 16 + l15) * 40 + q * 8);
#pragma unroll
        for (int j = 0; j < 4; ++j) {
            int n = wn * 64 + j * 16 + l15;
            bfr[j] = *(const short8*)(sB + n * 40 + ((q ^ ((n >> 3) & 3)) << 3));
        }
#pragma unroll
        for (int i = 0; i < 4; ++i)
#pragma unroll
            for (int j = 0; j < 4; ++j)
                acc[i][j] = __builtin_amdgcn_mfma_f32_16x16x32_bf16(af[i], bfr[j], acc[i][j], 0, 0, 0);
        __syncthreads();
    }
    if (tid < 128) sred[tid] = 0.f;
    __syncthreads();
#pragma unroll
    for (int i = 0; i < 4; ++i)
#pragma unroll
        for (int r = 0; r < 4; ++r) {
            float sv = 0.f;
#pragma unroll
            for (int j = 0; j < 4; ++j) {
                int n = n0 + wn * 64 + j * 16 + l15;
                sv += tanhf(acc[i][j][r]) * wv[n];
            }
#pragma unroll
            for (int o = 1; o < 16; o <<= 1) sv += __shfl_xor(sv, o, 64);
            if (l15 == 0) atomicAdd(&sred[wm * 64 + i * 16 + q * 4 + r], sv);
        }
    __syncthreads();
    if (tid < 128) atomicAdd(&scores[m0 + tid], sred[tid]);
}

// ---------- masked softmax over T ----------
__global__ void k_softmax(const float* __restrict__ scores, const int* __restrict__ lens,
                          float* __restrict__ alpha) {
    int b = blockIdx.x, t = threadIdx.x;
    int len = lens[b];
    float s = (t < len) ? scores[b * Tz + t] : -1e9f;
    float m = s;
#pragma unroll
    for (int o = 32; o; o >>= 1) m = fmaxf(m, __shfl_xor(m, o, 64));
    __shared__ float rA[2], rB[2];
    if ((t & 63) == 0) rA[t >> 6] = m;
    __syncthreads();
    m = fmaxf(rA[0], rA[1]);
    float e = expf(s - m);
    float sum = e;
#pragma unroll
    for (int o = 32; o; o >>= 1) sum += __shfl_xor(sum, o, 64);
    if ((t & 63) == 0) rB[t >> 6] = sum;
    __syncthreads();
    sum = rB[0] + rB[1];
    alpha[b * Tz + t] = e / sum;
}

// ---------- r[b,d] = sum_t alpha[b,t] * H[b,t,d] ----------
__global__ void k_r(const float* __restrict__ alpha, const unsigned short* __restrict__ Hbf,
                    float* __restrict__ rbuf) {
    int b = blockIdx.x;
    __shared__ float sal[Tz];
    if (threadIdx.x < Tz) sal[threadIdx.x] = alpha[b * Tz + threadIdx.x];
    __syncthreads();
    for (int d = threadIdx.x; d < DHz; d += blockDim.x) {
        float acc = 0.f;
        for (int t = 0; t < Tz; ++t) acc += sal[t] * bf2f(Hbf[((long)b * Tz + t) * DHz + d]);
        rbuf[(long)b * DHz + d] = acc;
    }
}

// ---------- h_star = tanh(r@Wp + H[:, -1, :]@Wx) ----------
__global__ void k_hstar(const float* __restrict__ rbuf, const unsigned short* __restrict__ Hbf,
                        const float* __restrict__ Wp, const float* __restrict__ Wx,
                        float* __restrict__ hst) {
    __shared__ float sA[16][65];
    __shared__ float sB[16][65];
    int bn = blockIdx.x * 64, bm = blockIdx.y * 64;
    int tx = threadIdx.x & 15, ty = threadIdx.x >> 4;
    float acc[4][4] = {};
    for (int src = 0; src < 2; ++src) {
        const float* Bm = src ? Wx : Wp;
        for (int k0 = 0; k0 < DHz; k0 += 16) {
            for (int l = threadIdx.x; l < 64 * 16; l += 256) {
                int mm = l >> 4, kk = l & 15;
                sA[kk][mm] = src ? bf2f(Hbf[((long)(bm + mm) * Tz + (Tz - 1)) * DHz + k0 + kk])
                                 : rbuf[(long)(bm + mm) * DHz + k0 + kk];
            }
            for (int l = threadIdx.x; l < 16 * 64; l += 256) {
                int kk = l >> 6, nn = l & 63;
                sB[kk][nn] = Bm[(long)(k0 + kk) * DHz + bn + nn];
            }
            __syncthreads();
            for (int k = 0; k < 16; ++k) {
                float a0[4], b0[4];
#pragma unroll
                for (int i = 0; i < 4; ++i) a0[i] = sA[k][ty * 4 + i];
#pragma unroll
                for (int j = 0; j < 4; ++j) b0[j] = sB[k][tx * 4 + j];
#pragma unroll
                for (int i = 0; i < 4; ++i)
#pragma unroll
                    for (int j = 0; j < 4; ++j) acc[i][j] += a0[i] * b0[j];
            }
            __syncthreads();
        }
    }
#pragma unroll
    for (int i = 0; i < 4; ++i)
#pragma unroll
        for (int j = 0; j < 4; ++j)
            hst[(long)(bm + ty * 4 + i) * DHz + bn + tx * 4 + j] = tanhf(acc[i][j]);
}

// ---------- logits ----------
__global__ void k_logits(const float* __restrict__ hst, const float* __restrict__ Wl,
                         const float* __restrict__ bl, float* __restrict__ out) {
    int b = blockIdx.x;
    int lane = threadIdx.x & 63, c = threadIdx.x >> 6;
    float s = 0.f;
    for (int k = lane; k < DHz; k += 64) s += hst[(long)b * DHz + k] * Wl[k * 3 + c];
#pragma unroll
    for (int o = 32; o; o >>= 1) s += __shfl_xor(s, o, 64);
    if (lane == 0) out[b * 3 + c] = s + bl[c];
}

extern "C" void kernel_launch(void* const* d_in, const int* in_sizes, int n_in,
                              void* d_out, int out_size, void* d_ws, size_t ws_size,
                              hipStream_t stream) {
    (void)in_sizes; (void)n_in; (void)out_size; (void)ws_size;
    const int*   sent   = (const int*)d_in[0];
    const int*   target = (const int*)d_in[1];
    const int*   lens   = (const int*)d_in[2];
    const float* emb    = (const float*)d_in[3];
    const float* temb   = (const float*)d_in[4];
    const float* W_ih   = (const float*)d_in[5];
    const float* W_hh   = (const float*)d_in[6];
    const float* b_lstm = (const float*)d_in[7];
    const float* Wh     = (const float*)d_in[8];
    // d_in[9] (Wv) and w[768:] provably cancel under softmax shift-invariance
    const float* wv     = (const float*)d_in[10];
    const float* Wp     = (const float*)d_in[11];
    const float* Wx     = (const float*)d_in[12];
    const float* W_lin  = (const float*)d_in[13];
    const float* b_lin  = (const float*)d_in[14];
    float* out = (float*)d_out;

    char* ws = (char*)d_ws;
    size_t off = 0;
    auto alloc = [&](size_t bytes) -> void* {
        void* p = ws + off;
        off = (off + bytes + 255) & ~(size_t)255;
        return p;
    };
    unsigned short* xW   = (unsigned short*)alloc((size_t)32768 * G4z * 2);   // 201 MB, row = t*256+b
    unsigned short* Hbf  = (unsigned short*)alloc((size_t)Bz * Tz * DHz * 2); // 50 MB, [b][t][d]
    unsigned short* Wihb = (unsigned short*)alloc((size_t)DWz * G4z * 2);
    unsigned short* Whhb = (unsigned short*)alloc((size_t)DHz * G4z * 2);
    unsigned short* Whb  = (unsigned short*)alloc((size_t)DHz * DHz * 2);
    float* tx     = (float*)alloc((size_t)Bz * DWz * 4);
    float* constg = (float*)alloc((size_t)Bz * G4z * 4);
    float* cbuf   = (float*)alloc((size_t)Bz * DHz * 4);
    float* scores = (float*)alloc((size_t)Bz * Tz * 4);
    float* alpha  = (float*)alloc((size_t)Bz * Tz * 4);
    float* rbuf   = (float*)alloc((size_t)Bz * DHz * 4);
    float* hst    = (float*)alloc((size_t)Bz * DHz * 4);

    k_cvt4<<<1024, 256, 0, stream>>>(W_ih, Wihb, DWz * G4z / 4);   // top 768 rows only
    k_cvt4<<<1024, 256, 0, stream>>>(W_hh, Whhb, DHz * G4z / 4);
    k_cvt4<<<512, 256, 0, stream>>>(Wh, Whb, DHz * DHz / 4);
    k_prep_tx<<<Bz, 256, 0, stream>>>(target, temb, tx);
    hipMemsetAsync(cbuf, 0, (size_t)Bz * DHz * 4, stream);
    hipMemsetAsync(scores, 0, (size_t)Bz * Tz * 4, stream);

    k_gemm_f32_bias<<<dim3(48, 4), 256, 0, stream>>>(tx, W_ih + (size_t)DWz * G4z, b_lstm,
                                                     constg, Bz, G4z, DWz, DWz, G4z);
    k_gemm_x<<<dim3(24, 256), 256, 0, stream>>>(emb, sent, Wihb, xW);
    for (int t = 0; t < Tz; ++t)
        k_lstm_step<<<48, 256, 0, stream>>>(t, xW, constg, Whhb, Hbf, cbuf, lens);
    k_scores<<<dim3(6, 256), 256, 0, stream>>>(Hbf, Whb, wv, scores);
    k_softmax<<<Bz, 128, 0, stream>>>(scores, lens, alpha);
    k_r<<<Bz, 256, 0, stream>>>(alpha, Hbf, rbuf);
    k_hstar<<<dim3(12, 4), 256, 0, stream>>>(rbuf, Hbf, Wp, Wx, hst);
    k_logits<<<Bz, 192, 0, stream>>>(hst, W_lin, b_lin, out);
}

// Round 2
// 5404.613 us; speedup vs baseline: 1.0369x; 1.0369x over previous
//
#include <hip/hip_runtime.h>
#include <hip/hip_cooperative_groups.h>
#include <stdint.h>

#define Bz 256
#define Tz 128
#define DWz 768
#define DHz 768
#define G4z 3072

typedef __attribute__((ext_vector_type(8))) short short8;
typedef __attribute__((ext_vector_type(4))) float f32x4;

__device__ __forceinline__ unsigned short f2bf(float x) {
    union { float f; unsigned int u; } v; v.f = x;
    unsigned int u = v.u;
    return (unsigned short)((u + 0x7fffu + ((u >> 16) & 1u)) >> 16);
}
__device__ __forceinline__ float bf2f(unsigned short h) {
    union { unsigned int u; float f; } v; v.u = ((unsigned int)h) << 16;
    return v.f;
}
__device__ __forceinline__ float sigm(float x) { return 1.0f / (1.0f + expf(-x)); }
__device__ __forceinline__ int sboff(int n, int k) {
    return n * 40 + ((((k >> 3) ^ ((n >> 3) & 3))) << 3) + (k & 7);
}

// ---------- fp32 -> bf16 bulk convert ----------
__global__ void k_cvt4(const float* __restrict__ src, unsigned short* __restrict__ dst, int n4) {
    int i = blockIdx.x * blockDim.x + threadIdx.x;
    int st = gridDim.x * blockDim.x;
    for (; i < n4; i += st) {
        float4 v = ((const float4*)src)[i];
        ushort4 o;
        o.x = f2bf(v.x); o.y = f2bf(v.y); o.z = f2bf(v.z); o.w = f2bf(v.w);
        ((ushort4*)dst)[i] = o;
    }
}

// ---------- gather aspect embedding ----------
__global__ void k_prep_tx(const int* __restrict__ target, const float* __restrict__ temb,
                          float* __restrict__ tx) {
    int b = blockIdx.x;
    long row = (long)target[b] * DWz;
    for (int d = threadIdx.x; d < DWz; d += blockDim.x)
        tx[b * DWz + d] = temb[row + d];
}

// ---------- Whh -> pre-swizzled bf16 blobs matching the persistent kernel's LDS layout ----
// WhhP[dblk][k0c][slot], slot = nl*4 + c  (16B each). Content: k-part q8 = c ^ ((nl>>1)&3),
// col = (nl>>4)*768 + dblk*16 + (nl&15), elements Whh[k0c*32 + q8*8 + e][col].
__global__ void k_prep_whh(const float* __restrict__ Whh, unsigned short* __restrict__ WhhP) {
    int id = blockIdx.x * 256 + threadIdx.x;   // [0, 48*6144)
    int dblk = id / 6144;
    int rem = id - dblk * 6144;
    int k0c = rem >> 8;
    int slot = rem & 255;
    int nl = slot >> 2, cc = slot & 3;
    int q8 = cc ^ ((nl >> 1) & 3);
    int k = k0c * 32 + q8 * 8;
    int col = (nl >> 4) * 768 + dblk * 16 + (nl & 15);
    alignas(16) unsigned short o[8];
#pragma unroll
    for (int e = 0; e < 8; ++e) o[e] = f2bf(Whh[(long)(k + e) * G4z + col]);
    *(int4*)(WhhP + (long)id * 8) = *(const int4*)o;
}

// ---------- generic fp32 tiled GEMM with bias (for const_gates) ----------
__global__ void k_gemm_f32_bias(const float* __restrict__ A, const float* __restrict__ Bm,
                                const float* __restrict__ bias, float* __restrict__ C,
                                int M, int N, int K, int lda, int ldb) {
    __shared__ float sA[16][65];
    __shared__ float sB[16][65];
    int bn = blockIdx.x * 64, bm = blockIdx.y * 64;
    int tx = threadIdx.x & 15, ty = threadIdx.x >> 4;
    float acc[4][4] = {};
    for (int k0 = 0; k0 < K; k0 += 16) {
        for (int l = threadIdx.x; l < 64 * 16; l += 256) {
            int m = l >> 4, k = l & 15;
            sA[k][m] = A[(long)(bm + m) * lda + k0 + k];
        }
        for (int l = threadIdx.x; l < 16 * 64; l += 256) {
            int k = l >> 6, n = l & 63;
            sB[k][n] = Bm[(long)(k0 + k) * ldb + bn + n];
        }
        __syncthreads();
        for (int k = 0; k < 16; ++k) {
            float a0[4], b0[4];
#pragma unroll
            for (int i = 0; i < 4; ++i) a0[i] = sA[k][ty * 4 + i];
#pragma unroll
            for (int j = 0; j < 4; ++j) b0[j] = sB[k][tx * 4 + j];
#pragma unroll
            for (int i = 0; i < 4; ++i)
#pragma unroll
                for (int j = 0; j < 4; ++j) acc[i][j] += a0[i] * b0[j];
        }
        __syncthreads();
    }
#pragma unroll
    for (int i = 0; i < 4; ++i)
#pragma unroll
        for (int j = 0; j < 4; ++j) {
            int m = bm + ty * 4 + i, n = bn + tx * 4 + j;
            C[(long)m * N + n] = acc[i][j] + bias[n];
        }
}

// ---------- xW = emb[sent] @ W_ih[:768]  (bf16 MFMA, row m' = t*256+b) ----------
__global__ __launch_bounds__(256) void k_gemm_x(const float* __restrict__ emb,
                                                const int* __restrict__ sent,
                                                const unsigned short* __restrict__ Wb,
                                                unsigned short* __restrict__ xW) {
    __shared__ unsigned short sA[128 * 40];
    __shared__ unsigned short sB[128 * 40];
    int tid = threadIdx.x;
    int n0 = blockIdx.x * 128;
    int m0 = blockIdx.y * 128;
    int wid = tid >> 6, lane = tid & 63, l15 = lane & 15, q = lane >> 4;
    int wm = wid >> 1, wn = wid & 1;

    int arow = tid >> 1;
    int kp = (tid & 1) * 16;
    int m = m0 + arow;
    int tt = m >> 8;
    int bb = m & 255;
    long gbase = (long)sent[bb * Tz + tt] * DWz;

    f32x4 acc[4][4];
    f32x4 zz = {0.f, 0.f, 0.f, 0.f};
#pragma unroll
    for (int i = 0; i < 4; ++i)
#pragma unroll
        for (int j = 0; j < 4; ++j) acc[i][j] = zz;

    for (int k0 = 0; k0 < DWz; k0 += 32) {
        {
            const float* src = emb + gbase + k0 + kp;
            alignas(16) unsigned short tmp[16];
#pragma unroll
            for (int it = 0; it < 4; ++it) {
                float4 v = ((const float4*)src)[it];
                tmp[it * 4 + 0] = f2bf(v.x); tmp[it * 4 + 1] = f2bf(v.y);
                tmp[it * 4 + 2] = f2bf(v.z); tmp[it * 4 + 3] = f2bf(v.w);
            }
            *(int4*)(sA + arow * 40 + kp) = *(const int4*)tmp;
            *(int4*)(sA + arow * 40 + kp + 8) = *(const int4*)(tmp + 8);
        }
#pragma unroll
        for (int it = 0; it < 2; ++it) {
            int s = tid + it * 256;
            int k = s >> 4;
            int n = (s & 15) * 8;
            int4 v = *(const int4*)(Wb + (long)(k0 + k) * G4z + n0 + n);
            const unsigned short* pv = (const unsigned short*)&v;
#pragma unroll
            for (int e = 0; e < 8; ++e) sB[sboff(n + e, k)] = pv[e];
        }
        __syncthreads();
        short8 af[4], bfr[4];
#pragma unroll
        for (int i = 0; i < 4; ++i)
            af[i] = *(const short8*)(sA + (wm * 64 + i * 16 + l15) * 40 + q * 8);
#pragma unroll
        for (int j = 0; j < 4; ++j) {
            int n = wn * 64 + j * 16 + l15;
            bfr[j] = *(const short8*)(sB + n * 40 + ((q ^ ((n >> 3) & 3)) << 3));
        }
#pragma unroll
        for (int i = 0; i < 4; ++i)
#pragma unroll
            for (int j = 0; j < 4; ++j)
                acc[i][j] = __builtin_amdgcn_mfma_f32_16x16x32_bf16(af[i], bfr[j], acc[i][j], 0, 0, 0);
        __syncthreads();
    }
#pragma unroll
    for (int i = 0; i < 4; ++i) {
        int row = m0 + wm * 64 + i * 16 + q * 4;
#pragma unroll
        for (int j = 0; j < 4; ++j) {
            int col = n0 + wn * 64 + j * 16 + l15;
#pragma unroll
            for (int r = 0; r < 4; ++r)
                xW[(long)(row + r) * G4z + col] = f2bf(acc[i][j][r]);
        }
    }
}

// ---------- persistent LSTM: all 128 steps, grid.sync between steps ----------
// 96 blocks: bm = blockIdx&1 (128 batch rows), dblk = blockIdx>>1 (16 d's of each gate).
// B (Whh slice, 768x64 bf16 = 96KB) LDS-resident for the whole kernel.
// A fragments loaded straight from global Hbf (no LDS, no barriers in K-loop).
// All 4 gates of (b,d) land in the same lane (gate = j frag, d = d0 + (lane&15)).
__global__ __launch_bounds__(256, 1) void k_lstm_all(int t0, int t1,
        const unsigned short* __restrict__ xW, const float* __restrict__ constg,
        const unsigned short* __restrict__ WhhP, unsigned short* __restrict__ Hbf,
        float* __restrict__ cbuf, const int* __restrict__ lens) {
    extern __shared__ unsigned short sB[];   // 96 KB
    int tid = threadIdx.x;
    int bm = blockIdx.x & 1;
    int dblk = blockIdx.x >> 1;
    int d0 = dblk * 16;
    int lane = tid & 63, wid = tid >> 6;
    int l15 = lane & 15, q = lane >> 4;
    int d = d0 + l15;

    {   // stage pre-swizzled B once
        const int4* src = (const int4*)WhhP + (long)dblk * 6144;
        for (int s = tid; s < 6144; s += 256) ((int4*)sB)[s] = src[s];
    }

    int brow[8];
    int lenr[8];
    float c[8], h[8];
#pragma unroll
    for (int i = 0; i < 2; ++i)
#pragma unroll
        for (int r = 0; r < 4; ++r) {
            int ir = i * 4 + r;
            int b = bm * 128 + wid * 32 + i * 16 + q * 4 + r;
            brow[ir] = b;
            lenr[ir] = lens[b];
            if (t0 > 0) {
                c[ir] = cbuf[(long)b * DHz + d];
                h[ir] = bf2f(Hbf[((long)b * Tz + (t0 - 1)) * DHz + d]);
            } else { c[ir] = 0.f; h[ir] = 0.f; }
        }

    // per-j LDS fragment base (shorts)
    int bbase[4];
#pragma unroll
    for (int j = 0; j < 4; ++j) {
        int nl = j * 16 + l15;
        bbase[j] = nl * 32 + ((q ^ ((nl >> 1) & 3)) << 3);
    }
    __syncthreads();

    cooperative_groups::grid_group grid = cooperative_groups::this_grid();

    for (int t = t0; t < t1; ++t) {
        // gate constants for this step (independent loads; overlap with K-loop)
        float xg[2][4][4];
#pragma unroll
        for (int i = 0; i < 2; ++i)
#pragma unroll
            for (int r = 0; r < 4; ++r) {
                int ir = i * 4 + r;
                long xbase = ((long)t * 256 + brow[ir]) * G4z + d;
                long cbase = (long)brow[ir] * G4z + d;
#pragma unroll
                for (int j = 0; j < 4; ++j)
                    xg[i][j][r] = bf2f(xW[xbase + j * 768]) + constg[cbase + j * 768];
            }

        f32x4 acc[2][4];
        f32x4 zz = {0.f, 0.f, 0.f, 0.f};
#pragma unroll
        for (int i = 0; i < 2; ++i)
#pragma unroll
            for (int j = 0; j < 4; ++j) acc[i][j] = zz;

        if (t > 0) {
            const unsigned short* ap0 = Hbf + ((long)(bm * 128 + wid * 32 + l15) * Tz + (t - 1)) * DHz + q * 8;
            const unsigned short* ap1 = ap0 + (long)16 * Tz * DHz;
#pragma unroll 6
            for (int k0c = 0; k0c < 24; ++k0c) {
                short8 a0 = *(const short8*)(ap0 + k0c * 32);
                short8 a1 = *(const short8*)(ap1 + k0c * 32);
                const unsigned short* bb = sB + k0c * 2048;
#pragma unroll
                for (int j = 0; j < 4; ++j) {
                    short8 bf = *(const short8*)(bb + bbase[j]);
                    acc[0][j] = __builtin_amdgcn_mfma_f32_16x16x32_bf16(a0, bf, acc[0][j], 0, 0, 0);
                    acc[1][j] = __builtin_amdgcn_mfma_f32_16x16x32_bf16(a1, bf, acc[1][j], 0, 0, 0);
                }
            }
        }

        // in-register gate pointwise
#pragma unroll
        for (int i = 0; i < 2; ++i)
#pragma unroll
            for (int r = 0; r < 4; ++r) {
                int ir = i * 4 + r;
                float gi = acc[i][0][r] + xg[i][0][r];
                float gf = acc[i][1][r] + xg[i][1][r];
                float gg = acc[i][2][r] + xg[i][2][r];
                float go = acc[i][3][r] + xg[i][3][r];
                float cn = sigm(gf) * c[ir] + sigm(gi) * tanhf(gg);
                float hn = sigm(go) * tanhf(cn);
                bool upd = t < lenr[ir];
                c[ir] = upd ? cn : c[ir];
                h[ir] = upd ? hn : h[ir];
                Hbf[((long)brow[ir] * Tz + t) * DHz + d] = f2bf(h[ir]);
            }

        if (t + 1 < t1) {
            __threadfence();
            grid.sync();
        }
    }
    // persist c for (non-cooperative) per-step chaining
#pragma unroll
    for (int ir = 0; ir < 8; ++ir) cbuf[(long)brow[ir] * DHz + d] = c[ir];
}

// ---------- scores[b,t] = sum_d w[d]*tanh( (H@Wh)[b,t,d] ) ----------
__global__ __launch_bounds__(256) void k_scores(const unsigned short* __restrict__ Hbf,
                                                const unsigned short* __restrict__ Whb,
                                                const float* __restrict__ wv,
                                                float* __restrict__ scores) {
    __shared__ unsigned short sA[128 * 40];
    __shared__ unsigned short sB[128 * 40];
    __shared__ float sred[128];
    int tid = threadIdx.x;
    int n0 = blockIdx.x * 128;
    int m0 = blockIdx.y * 128;
    int wid = tid >> 6, lane = tid & 63, l15 = lane & 15, q = lane >> 4;
    int wm = wid >> 1, wn = wid & 1;

    f32x4 acc[4][4];
    f32x4 zz = {0.f, 0.f, 0.f, 0.f};
#pragma unroll
    for (int i = 0; i < 4; ++i)
#pragma unroll
        for (int j = 0; j < 4; ++j) acc[i][j] = zz;

    int arow = tid >> 1;
    int kp = (tid & 1) * 16;
    const unsigned short* asrc = Hbf + (long)(m0 + arow) * DHz;

    for (int k0 = 0; k0 < DHz; k0 += 32) {
        *(int4*)(sA + arow * 40 + kp) = *(const int4*)(asrc + k0 + kp);
        *(int4*)(sA + arow * 40 + kp + 8) = *(const int4*)(asrc + k0 + kp + 8);
#pragma unroll
        for (int it = 0; it < 2; ++it) {
            int s = tid + it * 256;
            int k = s >> 4;
            int n = (s & 15) * 8;
            int4 v = *(const int4*)(Whb + (long)(k0 + k) * DHz + n0 + n);
            const unsigned short* pv = (const unsigned short*)&v;
#pragma unroll
            for (int e = 0; e < 8; ++e) sB[sboff(n + e, k)] = pv[e];
        }
        __syncthreads();
        short8 af[4], bfr[4];
#pragma unroll
        for (int i = 0; i < 4; ++i)
            af[i] = *(const short8*)(sA + (wm * 64 + i * 16 + l15) * 40 + q * 8);
#pragma unroll
        for (int j = 0; j < 4; ++j) {
            int n = wn * 64 + j * 16 + l15;
            bfr[j] = *(const short8*)(sB + n * 40 + ((q ^ ((n >> 3) & 3)) << 3));
        }
#pragma unroll
        for (int i = 0; i < 4; ++i)
#pragma unroll
            for (int j = 0; j < 4; ++j)
                acc[i][j] = __builtin_amdgcn_mfma_f32_16x16x32_bf16(af[i], bfr[j], acc[i][j], 0, 0, 0);
        __syncthreads();
    }
    if (tid < 128) sred[tid] = 0.f;
    __syncthreads();
#pragma unroll
    for (int i = 0; i < 4; ++i)
#pragma unroll
        for (int r = 0; r < 4; ++r) {
            float sv = 0.f;
#pragma unroll
            for (int j = 0; j < 4; ++j) {
                int n = n0 + wn * 64 + j * 16 + l15;
                sv += tanhf(acc[i][j][r]) * wv[n];
            }
#pragma unroll
            for (int o = 1; o < 16; o <<= 1) sv += __shfl_xor(sv, o, 64);
            if (l15 == 0) atomicAdd(&sred[wm * 64 + i * 16 + q * 4 + r], sv);
        }
    __syncthreads();
    if (tid < 128) atomicAdd(&scores[m0 + tid], sred[tid]);
}

// ---------- masked softmax over T ----------
__global__ void k_softmax(const float* __restrict__ scores, const int* __restrict__ lens,
                          float* __restrict__ alpha) {
    int b = blockIdx.x, t = threadIdx.x;
    int len = lens[b];
    float s = (t < len) ? scores[b * Tz + t] : -1e9f;
    float m = s;
#pragma unroll
    for (int o = 32; o; o >>= 1) m = fmaxf(m, __shfl_xor(m, o, 64));
    __shared__ float rA[2], rB[2];
    if ((t & 63) == 0) rA[t >> 6] = m;
    __syncthreads();
    m = fmaxf(rA[0], rA[1]);
    float e = expf(s - m);
    float sum = e;
#pragma unroll
    for (int o = 32; o; o >>= 1) sum += __shfl_xor(sum, o, 64);
    if ((t & 63) == 0) rB[t >> 6] = sum;
    __syncthreads();
    sum = rB[0] + rB[1];
    alpha[b * Tz + t] = e / sum;
}

// ---------- r[b,d] = sum_t alpha[b,t] * H[b,t,d] ----------
__global__ void k_r(const float* __restrict__ alpha, const unsigned short* __restrict__ Hbf,
                    float* __restrict__ rbuf) {
    int b = blockIdx.x;
    __shared__ float sal[Tz];
    if (threadIdx.x < Tz) sal[threadIdx.x] = alpha[b * Tz + threadIdx.x];
    __syncthreads();
    for (int d = threadIdx.x; d < DHz; d += blockDim.x) {
        float acc = 0.f;
        for (int t = 0; t < Tz; ++t) acc += sal[t] * bf2f(Hbf[((long)b * Tz + t) * DHz + d]);
        rbuf[(long)b * DHz + d] = acc;
    }
}

// ---------- h_star = tanh(r@Wp + H[:, -1, :]@Wx) ----------
__global__ void k_hstar(const float* __restrict__ rbuf, const unsigned short* __restrict__ Hbf,
                        const float* __restrict__ Wp, const float* __restrict__ Wx,
                        float* __restrict__ hst) {
    __shared__ float sA[16][65];
    __shared__ float sB[16][65];
    int bn = blockIdx.x * 64, bm = blockIdx.y * 64;
    int tx = threadIdx.x & 15, ty = threadIdx.x >> 4;
    float acc[4][4] = {};
    for (int src = 0; src < 2; ++src) {
        const float* Bm = src ? Wx : Wp;
        for (int k0 = 0; k0 < DHz; k0 += 16) {
            for (int l = threadIdx.x; l < 64 * 16; l += 256) {
                int mm = l >> 4, kk = l & 15;
                sA[kk][mm] = src ? bf2f(Hbf[((long)(bm + mm) * Tz + (Tz - 1)) * DHz + k0 + kk])
                                 : rbuf[(long)(bm + mm) * DHz + k0 + kk];
            }
            for (int l = threadIdx.x; l < 16 * 64; l += 256) {
                int kk = l >> 6, nn = l & 63;
                sB[kk][nn] = Bm[(long)(k0 + kk) * DHz + bn + nn];
            }
            __syncthreads();
            for (int k = 0; k < 16; ++k) {
                float a0[4], b0[4];
#pragma unroll
                for (int i = 0; i < 4; ++i) a0[i] = sA[k][ty * 4 + i];
#pragma unroll
                for (int j = 0; j < 4; ++j) b0[j] = sB[k][tx * 4 + j];
#pragma unroll
                for (int i = 0; i < 4; ++i)
#pragma unroll
                    for (int j = 0; j < 4; ++j) acc[i][j] += a0[i] * b0[j];
            }
            __syncthreads();
        }
    }
#pragma unroll
    for (int i = 0; i < 4; ++i)
#pragma unroll
        for (int j = 0; j < 4; ++j)
            hst[(long)(bm + ty * 4 + i) * DHz + bn + tx * 4 + j] = tanhf(acc[i][j]);
}

// ---------- logits ----------
__global__ void k_logits(const float* __restrict__ hst, const float* __restrict__ Wl,
                         const float* __restrict__ bl, float* __restrict__ out) {
    int b = blockIdx.x;
    int lane = threadIdx.x & 63, c = threadIdx.x >> 6;
    float s = 0.f;
    for (int k = lane; k < DHz; k += 64) s += hst[(long)b * DHz + k] * Wl[k * 3 + c];
#pragma unroll
    for (int o = 32; o; o >>= 1) s += __shfl_xor(s, o, 64);
    if (lane == 0) out[b * 3 + c] = s + bl[c];
}

extern "C" void kernel_launch(void* const* d_in, const int* in_sizes, int n_in,
                              void* d_out, int out_size, void* d_ws, size_t ws_size,
                              hipStream_t stream) {
    (void)in_sizes; (void)n_in; (void)out_size; (void)ws_size;
    const int*   sent   = (const int*)d_in[0];
    const int*   target = (const int*)d_in[1];
    const int*   lens   = (const int*)d_in[2];
    const float* emb    = (const float*)d_in[3];
    const float* temb   = (const float*)d_in[4];
    const float* W_ih   = (const float*)d_in[5];
    const float* W_hh   = (const float*)d_in[6];
    const float* b_lstm = (const float*)d_in[7];
    const float* Wh     = (const float*)d_in[8];
    const float* wv     = (const float*)d_in[10];
    const float* Wp     = (const float*)d_in[11];
    const float* Wx     = (const float*)d_in[12];
    const float* W_lin  = (const float*)d_in[13];
    const float* b_lin  = (const float*)d_in[14];
    float* out = (float*)d_out;

    char* ws = (char*)d_ws;
    size_t off = 0;
    auto alloc = [&](size_t bytes) -> void* {
        void* p = ws + off;
        off = (off + bytes + 255) & ~(size_t)255;
        return p;
    };
    unsigned short* xW   = (unsigned short*)alloc((size_t)32768 * G4z * 2);
    unsigned short* Hbf  = (unsigned short*)alloc((size_t)Bz * Tz * DHz * 2);
    unsigned short* Wihb = (unsigned short*)alloc((size_t)DWz * G4z * 2);
    unsigned short* WhhP = (unsigned short*)alloc((size_t)48 * 6144 * 16);
    unsigned short* Whb  = (unsigned short*)alloc((size_t)DHz * DHz * 2);
    float* tx     = (float*)alloc((size_t)Bz * DWz * 4);
    float* constg = (float*)alloc((size_t)Bz * G4z * 4);
    float* cbuf   = (float*)alloc((size_t)Bz * DHz * 4);
    float* scores = (float*)alloc((size_t)Bz * Tz * 4);
    float* alpha  = (float*)alloc((size_t)Bz * Tz * 4);
    float* rbuf   = (float*)alloc((size_t)Bz * DHz * 4);
    float* hst    = (float*)alloc((size_t)Bz * DHz * 4);

    k_cvt4<<<1024, 256, 0, stream>>>(W_ih, Wihb, DWz * G4z / 4);
    k_cvt4<<<512, 256, 0, stream>>>(Wh, Whb, DHz * DHz / 4);
    k_prep_whh<<<1152, 256, 0, stream>>>(W_hh, WhhP);
    k_prep_tx<<<Bz, 256, 0, stream>>>(target, temb, tx);
    hipMemsetAsync(scores, 0, (size_t)Bz * Tz * 4, stream);

    k_gemm_f32_bias<<<dim3(48, 4), 256, 0, stream>>>(tx, W_ih + (size_t)DWz * G4z, b_lstm,
                                                     constg, Bz, G4z, DWz, DWz, G4z);
    k_gemm_x<<<dim3(24, 256), 256, 0, stream>>>(emb, sent, Wihb, xW);

    // persistent cooperative LSTM (fallback: per-step regular launches)
    hipFuncSetAttribute((const void*)k_lstm_all,
                        hipFuncAttributeMaxDynamicSharedMemorySize, 98304);
    int t0v = 0, t1v = Tz;
    const unsigned short* xWp = xW;
    const float* cgp = constg;
    const unsigned short* whp = WhhP;
    unsigned short* hbp = Hbf;
    float* cbp = cbuf;
    const int* lnp = lens;
    void* kargs[] = {&t0v, &t1v, &xWp, &cgp, &whp, &hbp, &cbp, &lnp};
    hipError_t ce = hipLaunchCooperativeKernel(reinterpret_cast<void*>(k_lstm_all),
                                               dim3(96), dim3(256), kargs, 98304, stream);
    if (ce != hipSuccess) {
        for (int t = 0; t < Tz; ++t)
            k_lstm_all<<<96, 256, 98304, stream>>>(t, t + 1, xW, constg, WhhP, Hbf, cbuf, lens);
    }

    k_scores<<<dim3(6, 256), 256, 0, stream>>>(Hbf, Whb, wv, scores);
    k_softmax<<<Bz, 128, 0, stream>>>(scores, lens, alpha);
    k_r<<<Bz, 256, 0, stream>>>(alpha, Hbf, rbuf);
    k_hstar<<<dim3(12, 4), 256, 0, stream>>>(rbuf, Hbf, Wp, Wx, hst);
    k_logits<<<Bz, 192, 0, stream>>>(hst, W_lin, b_lin, out);
}

// Round 3
// 3849.557 us; speedup vs baseline: 1.4558x; 1.4040x over previous
//
#include <hip/hip_runtime.h>
#include <stdint.h>

#define Bz 256
#define Tz 128
#define DWz 768
#define DHz 768
#define G4z 3072
#define NBLK 96

typedef __attribute__((ext_vector_type(8))) short short8;
typedef __attribute__((ext_vector_type(4))) float f32x4;

__device__ __forceinline__ unsigned short f2bf(float x) {
    union { float f; unsigned int u; } v; v.f = x;
    unsigned int u = v.u;
    return (unsigned short)((u + 0x7fffu + ((u >> 16) & 1u)) >> 16);
}
__device__ __forceinline__ float bf2f(unsigned short h) {
    union { unsigned int u; float f; } v; v.u = ((unsigned int)h) << 16;
    return v.f;
}
__device__ __forceinline__ float sigm(float x) { return 1.0f / (1.0f + expf(-x)); }
__device__ __forceinline__ int sboff(int n, int k) {
    return n * 40 + ((((k >> 3) ^ ((n >> 3) & 3))) << 3) + (k & 7);
}

// ---------- fp32 -> bf16 bulk convert ----------
__global__ void k_cvt4(const float* __restrict__ src, unsigned short* __restrict__ dst, int n4) {
    int i = blockIdx.x * blockDim.x + threadIdx.x;
    int st = gridDim.x * blockDim.x;
    for (; i < n4; i += st) {
        float4 v = ((const float4*)src)[i];
        ushort4 o;
        o.x = f2bf(v.x); o.y = f2bf(v.y); o.z = f2bf(v.z); o.w = f2bf(v.w);
        ((ushort4*)dst)[i] = o;
    }
}

// ---------- gather aspect embedding ----------
__global__ void k_prep_tx(const int* __restrict__ target, const float* __restrict__ temb,
                          float* __restrict__ tx) {
    int b = blockIdx.x;
    long row = (long)target[b] * DWz;
    for (int d = threadIdx.x; d < DWz; d += blockDim.x)
        tx[b * DWz + d] = temb[row + d];
}

// ---------- Whh -> pre-swizzled bf16 blobs matching the persistent kernel's LDS layout ----
__global__ void k_prep_whh(const float* __restrict__ Whh, unsigned short* __restrict__ WhhP) {
    int id = blockIdx.x * 256 + threadIdx.x;   // [0, 48*6144)
    int dblk = id / 6144;
    int rem = id - dblk * 6144;
    int k0c = rem >> 8;
    int slot = rem & 255;
    int nl = slot >> 2, cc = slot & 3;
    int q8 = cc ^ ((nl >> 1) & 3);
    int k = k0c * 32 + q8 * 8;
    int col = (nl >> 4) * 768 + dblk * 16 + (nl & 15);
    alignas(16) unsigned short o[8];
#pragma unroll
    for (int e = 0; e < 8; ++e) o[e] = f2bf(Whh[(long)(k + e) * G4z + col]);
    *(int4*)(WhhP + (long)id * 8) = *(const int4*)o;
}

// ---------- generic fp32 tiled GEMM with bias (for const_gates) ----------
__global__ void k_gemm_f32_bias(const float* __restrict__ A, const float* __restrict__ Bm,
                                const float* __restrict__ bias, float* __restrict__ C,
                                int M, int N, int K, int lda, int ldb) {
    __shared__ float sA[16][65];
    __shared__ float sB[16][65];
    int bn = blockIdx.x * 64, bm = blockIdx.y * 64;
    int tx = threadIdx.x & 15, ty = threadIdx.x >> 4;
    float acc[4][4] = {};
    for (int k0 = 0; k0 < K; k0 += 16) {
        for (int l = threadIdx.x; l < 64 * 16; l += 256) {
            int m = l >> 4, k = l & 15;
            sA[k][m] = A[(long)(bm + m) * lda + k0 + k];
        }
        for (int l = threadIdx.x; l < 16 * 64; l += 256) {
            int k = l >> 6, n = l & 63;
            sB[k][n] = Bm[(long)(k0 + k) * ldb + bn + n];
        }
        __syncthreads();
        for (int k = 0; k < 16; ++k) {
            float a0[4], b0[4];
#pragma unroll
            for (int i = 0; i < 4; ++i) a0[i] = sA[k][ty * 4 + i];
#pragma unroll
            for (int j = 0; j < 4; ++j) b0[j] = sB[k][tx * 4 + j];
#pragma unroll
            for (int i = 0; i < 4; ++i)
#pragma unroll
                for (int j = 0; j < 4; ++j) acc[i][j] += a0[i] * b0[j];
        }
        __syncthreads();
    }
#pragma unroll
    for (int i = 0; i < 4; ++i)
#pragma unroll
        for (int j = 0; j < 4; ++j) {
            int m = bm + ty * 4 + i, n = bn + tx * 4 + j;
            C[(long)m * N + n] = acc[i][j] + bias[n];
        }
}

// ---------- xW = emb[sent] @ W_ih[:768]  (bf16 MFMA, row m' = t*256+b) ----------
__global__ __launch_bounds__(256) void k_gemm_x(const float* __restrict__ emb,
                                                const int* __restrict__ sent,
                                                const unsigned short* __restrict__ Wb,
                                                unsigned short* __restrict__ xW) {
    __shared__ unsigned short sA[128 * 40];
    __shared__ unsigned short sB[128 * 40];
    int tid = threadIdx.x;
    int n0 = blockIdx.x * 128;
    int m0 = blockIdx.y * 128;
    int wid = tid >> 6, lane = tid & 63, l15 = lane & 15, q = lane >> 4;
    int wm = wid >> 1, wn = wid & 1;

    int arow = tid >> 1;
    int kp = (tid & 1) * 16;
    int m = m0 + arow;
    int tt = m >> 8;
    int bb = m & 255;
    long gbase = (long)sent[bb * Tz + tt] * DWz;

    f32x4 acc[4][4];
    f32x4 zz = {0.f, 0.f, 0.f, 0.f};
#pragma unroll
    for (int i = 0; i < 4; ++i)
#pragma unroll
        for (int j = 0; j < 4; ++j) acc[i][j] = zz;

    for (int k0 = 0; k0 < DWz; k0 += 32) {
        {
            const float* src = emb + gbase + k0 + kp;
            alignas(16) unsigned short tmp[16];
#pragma unroll
            for (int it = 0; it < 4; ++it) {
                float4 v = ((const float4*)src)[it];
                tmp[it * 4 + 0] = f2bf(v.x); tmp[it * 4 + 1] = f2bf(v.y);
                tmp[it * 4 + 2] = f2bf(v.z); tmp[it * 4 + 3] = f2bf(v.w);
            }
            *(int4*)(sA + arow * 40 + kp) = *(const int4*)tmp;
            *(int4*)(sA + arow * 40 + kp + 8) = *(const int4*)(tmp + 8);
        }
#pragma unroll
        for (int it = 0; it < 2; ++it) {
            int s = tid + it * 256;
            int k = s >> 4;
            int n = (s & 15) * 8;
            int4 v = *(const int4*)(Wb + (long)(k0 + k) * G4z + n0 + n);
            const unsigned short* pv = (const unsigned short*)&v;
#pragma unroll
            for (int e = 0; e < 8; ++e) sB[sboff(n + e, k)] = pv[e];
        }
        __syncthreads();
        short8 af[4], bfr[4];
#pragma unroll
        for (int i = 0; i < 4; ++i)
            af[i] = *(const short8*)(sA + (wm * 64 + i * 16 + l15) * 40 + q * 8);
#pragma unroll
        for (int j = 0; j < 4; ++j) {
            int n = wn * 64 + j * 16 + l15;
            bfr[j] = *(const short8*)(sB + n * 40 + ((q ^ ((n >> 3) & 3)) << 3));
        }
#pragma unroll
        for (int i = 0; i < 4; ++i)
#pragma unroll
            for (int j = 0; j < 4; ++j)
                acc[i][j] = __builtin_amdgcn_mfma_f32_16x16x32_bf16(af[i], bfr[j], acc[i][j], 0, 0, 0);
        __syncthreads();
    }
#pragma unroll
    for (int i = 0; i < 4; ++i) {
        int row = m0 + wm * 64 + i * 16 + q * 4;
#pragma unroll
        for (int j = 0; j < 4; ++j) {
            int col = n0 + wn * 64 + j * 16 + l15;
#pragma unroll
            for (int r = 0; r < 4; ++r)
                xW[(long)(row + r) * G4z + col] = f2bf(acc[i][j][r]);
        }
    }
}

// ---------- persistent LSTM with hand-rolled grid barrier ----------
// 96 blocks: bm = blockIdx&1 (128 batch rows), dblk = blockIdx>>1 (16 d's of each gate).
// Whh slice (768x64 bf16 = 96KB) LDS-resident. A frags straight from global.
// Barrier: monotonic counter, release fence (wbl2) before arrive, acquire fence
// (inv) after release — ~2-3us vs ~32us for CG grid.sync.
__global__ __launch_bounds__(256, 1) void k_lstm_all(int t0, int t1,
        const unsigned short* __restrict__ xW, const float* __restrict__ constg,
        const unsigned short* __restrict__ WhhP, unsigned short* __restrict__ Hbf,
        float* __restrict__ cbuf, const int* __restrict__ lens,
        unsigned* __restrict__ bar) {
    extern __shared__ unsigned short sB[];   // 96 KB
    int tid = threadIdx.x;
    int bm = blockIdx.x & 1;
    int dblk = blockIdx.x >> 1;
    int d0 = dblk * 16;
    int lane = tid & 63, wid = tid >> 6;
    int l15 = lane & 15, q = lane >> 4;
    int d = d0 + l15;

    {   // stage pre-swizzled B once
        const int4* src = (const int4*)WhhP + (long)dblk * 6144;
        for (int s = tid; s < 6144; s += 256) ((int4*)sB)[s] = src[s];
    }

    int brow[8];
    int lenr[8];
    float c[8], h[8];
#pragma unroll
    for (int i = 0; i < 2; ++i)
#pragma unroll
        for (int r = 0; r < 4; ++r) {
            int ir = i * 4 + r;
            int b = bm * 128 + wid * 32 + i * 16 + q * 4 + r;
            brow[ir] = b;
            lenr[ir] = lens[b];
            if (t0 > 0) {
                c[ir] = cbuf[(long)b * DHz + d];
                h[ir] = bf2f(Hbf[((long)b * Tz + (t0 - 1)) * DHz + d]);
            } else { c[ir] = 0.f; h[ir] = 0.f; }
        }

    int bbase[4];
#pragma unroll
    for (int j = 0; j < 4; ++j) {
        int nl = j * 16 + l15;
        bbase[j] = nl * 32 + ((q ^ ((nl >> 1) & 3)) << 3);
    }
    __syncthreads();

    // prefetch gate constants for step t0
    float xg[2][4][4];
#pragma unroll
    for (int i = 0; i < 2; ++i)
#pragma unroll
        for (int r = 0; r < 4; ++r) {
            int ir = i * 4 + r;
            long xbase = ((long)t0 * 256 + brow[ir]) * G4z + d;
            long cbase = (long)brow[ir] * G4z + d;
#pragma unroll
            for (int j = 0; j < 4; ++j)
                xg[i][j][r] = bf2f(xW[xbase + j * 768]) + constg[cbase + j * 768];
        }

    for (int t = t0; t < t1; ++t) {
        f32x4 acc[2][4];
        f32x4 zz = {0.f, 0.f, 0.f, 0.f};
#pragma unroll
        for (int i = 0; i < 2; ++i)
#pragma unroll
            for (int j = 0; j < 4; ++j) acc[i][j] = zz;

        if (t > 0) {
            const unsigned short* ap0 = Hbf + ((long)(bm * 128 + wid * 32 + l15) * Tz + (t - 1)) * DHz + q * 8;
            const unsigned short* ap1 = ap0 + (long)16 * Tz * DHz;
#pragma unroll 6
            for (int k0c = 0; k0c < 24; ++k0c) {
                short8 a0 = *(const short8*)(ap0 + k0c * 32);
                short8 a1 = *(const short8*)(ap1 + k0c * 32);
                const unsigned short* bb = sB + k0c * 2048;
#pragma unroll
                for (int j = 0; j < 4; ++j) {
                    short8 bf = *(const short8*)(bb + bbase[j]);
                    acc[0][j] = __builtin_amdgcn_mfma_f32_16x16x32_bf16(a0, bf, acc[0][j], 0, 0, 0);
                    acc[1][j] = __builtin_amdgcn_mfma_f32_16x16x32_bf16(a1, bf, acc[1][j], 0, 0, 0);
                }
            }
        }

        // in-register gate pointwise
#pragma unroll
        for (int i = 0; i < 2; ++i)
#pragma unroll
            for (int r = 0; r < 4; ++r) {
                int ir = i * 4 + r;
                float gi = acc[i][0][r] + xg[i][0][r];
                float gf = acc[i][1][r] + xg[i][1][r];
                float gg = acc[i][2][r] + xg[i][2][r];
                float go = acc[i][3][r] + xg[i][3][r];
                float cn = sigm(gf) * c[ir] + sigm(gi) * tanhf(gg);
                float hn = sigm(go) * tanhf(cn);
                bool upd = t < lenr[ir];
                c[ir] = upd ? cn : c[ir];
                h[ir] = upd ? hn : h[ir];
                Hbf[((long)brow[ir] * Tz + t) * DHz + d] = f2bf(h[ir]);
            }

        if (t + 1 < t1) {
            // prefetch next step's gate constants BEFORE the barrier (the acquire
            // fence would otherwise forbid hoisting these loads)
#pragma unroll
            for (int i = 0; i < 2; ++i)
#pragma unroll
                for (int r = 0; r < 4; ++r) {
                    int ir = i * 4 + r;
                    long xbase = ((long)(t + 1) * 256 + brow[ir]) * G4z + d;
                    long cbase = (long)brow[ir] * G4z + d;
#pragma unroll
                    for (int j = 0; j < 4; ++j)
                        xg[i][j][r] = bf2f(xW[xbase + j * 768]) + constg[cbase + j * 768];
                }
            __syncthreads();   // all waves' h-stores are in (local-XCD) L2
            if (tid == 0) {
                __builtin_amdgcn_fence(__ATOMIC_RELEASE, "agent");  // wb dirty L2
                __hip_atomic_fetch_add(bar, 1u, __ATOMIC_RELAXED, __HIP_MEMORY_SCOPE_AGENT);
                unsigned target = (unsigned)(t - t0 + 1) * NBLK;
                while (__hip_atomic_load(bar, __ATOMIC_RELAXED, __HIP_MEMORY_SCOPE_AGENT) < target)
                    __builtin_amdgcn_s_sleep(2);
            }
            __syncthreads();
            __builtin_amdgcn_fence(__ATOMIC_ACQUIRE, "agent");      // inv stale lines
        }
    }
#pragma unroll
    for (int ir = 0; ir < 8; ++ir) cbuf[(long)brow[ir] * DHz + d] = c[ir];
}

// ---------- scores[b,t] = sum_d w[d]*tanh( (H@Wh)[b,t,d] ) ----------
__global__ __launch_bounds__(256) void k_scores(const unsigned short* __restrict__ Hbf,
                                                const unsigned short* __restrict__ Whb,
                                                const float* __restrict__ wv,
                                                float* __restrict__ scores) {
    __shared__ unsigned short sA[128 * 40];
    __shared__ unsigned short sB[128 * 40];
    __shared__ float sred[128];
    int tid = threadIdx.x;
    int n0 = blockIdx.x * 128;
    int m0 = blockIdx.y * 128;
    int wid = tid >> 6, lane = tid & 63, l15 = lane & 15, q = lane >> 4;
    int wm = wid >> 1, wn = wid & 1;

    f32x4 acc[4][4];
    f32x4 zz = {0.f, 0.f, 0.f, 0.f};
#pragma unroll
    for (int i = 0; i < 4; ++i)
#pragma unroll
        for (int j = 0; j < 4; ++j) acc[i][j] = zz;

    int arow = tid >> 1;
    int kp = (tid & 1) * 16;
    const unsigned short* asrc = Hbf + (long)(m0 + arow) * DHz;

    for (int k0 = 0; k0 < DHz; k0 += 32) {
        *(int4*)(sA + arow * 40 + kp) = *(const int4*)(asrc + k0 + kp);
        *(int4*)(sA + arow * 40 + kp + 8) = *(const int4*)(asrc + k0 + kp + 8);
#pragma unroll
        for (int it = 0; it < 2; ++it) {
            int s = tid + it * 256;
            int k = s >> 4;
            int n = (s & 15) * 8;
            int4 v = *(const int4*)(Whb + (long)(k0 + k) * DHz + n0 + n);
            const unsigned short* pv = (const unsigned short*)&v;
#pragma unroll
            for (int e = 0; e < 8; ++e) sB[sboff(n + e, k)] = pv[e];
        }
        __syncthreads();
        short8 af[4], bfr[4];
#pragma unroll
        for (int i = 0; i < 4; ++i)
            af[i] = *(const short8*)(sA + (wm * 64 + i * 16 + l15) * 40 + q * 8);
#pragma unroll
        for (int j = 0; j < 4; ++j) {
            int n = wn * 64 + j * 16 + l15;
            bfr[j] = *(const short8*)(sB + n * 40 + ((q ^ ((n >> 3) & 3)) << 3));
        }
#pragma unroll
        for (int i = 0; i < 4; ++i)
#pragma unroll
            for (int j = 0; j < 4; ++j)
                acc[i][j] = __builtin_amdgcn_mfma_f32_16x16x32_bf16(af[i], bfr[j], acc[i][j], 0, 0, 0);
        __syncthreads();
    }
    if (tid < 128) sred[tid] = 0.f;
    __syncthreads();
#pragma unroll
    for (int i = 0; i < 4; ++i)
#pragma unroll
        for (int r = 0; r < 4; ++r) {
            float sv = 0.f;
#pragma unroll
            for (int j = 0; j < 4; ++j) {
                int n = n0 + wn * 64 + j * 16 + l15;
                sv += tanhf(acc[i][j][r]) * wv[n];
            }
#pragma unroll
            for (int o = 1; o < 16; o <<= 1) sv += __shfl_xor(sv, o, 64);
            if (l15 == 0) atomicAdd(&sred[wm * 64 + i * 16 + q * 4 + r], sv);
        }
    __syncthreads();
    if (tid < 128) atomicAdd(&scores[m0 + tid], sred[tid]);
}

// ---------- masked softmax over T ----------
__global__ void k_softmax(const float* __restrict__ scores, const int* __restrict__ lens,
                          float* __restrict__ alpha) {
    int b = blockIdx.x, t = threadIdx.x;
    int len = lens[b];
    float s = (t < len) ? scores[b * Tz + t] : -1e9f;
    float m = s;
#pragma unroll
    for (int o = 32; o; o >>= 1) m = fmaxf(m, __shfl_xor(m, o, 64));
    __shared__ float rA[2], rB[2];
    if ((t & 63) == 0) rA[t >> 6] = m;
    __syncthreads();
    m = fmaxf(rA[0], rA[1]);
    float e = expf(s - m);
    float sum = e;
#pragma unroll
    for (int o = 32; o; o >>= 1) sum += __shfl_xor(sum, o, 64);
    if ((t & 63) == 0) rB[t >> 6] = sum;
    __syncthreads();
    sum = rB[0] + rB[1];
    alpha[b * Tz + t] = e / sum;
}

// ---------- r[b,d] = sum_t alpha[b,t] * H[b,t,d] ----------
__global__ void k_r(const float* __restrict__ alpha, const unsigned short* __restrict__ Hbf,
                    float* __restrict__ rbuf) {
    int b = blockIdx.x;
    __shared__ float sal[Tz];
    if (threadIdx.x < Tz) sal[threadIdx.x] = alpha[b * Tz + threadIdx.x];
    __syncthreads();
    for (int d = threadIdx.x; d < DHz; d += blockDim.x) {
        float acc = 0.f;
        for (int t = 0; t < Tz; ++t) acc += sal[t] * bf2f(Hbf[((long)b * Tz + t) * DHz + d]);
        rbuf[(long)b * DHz + d] = acc;
    }
}

// ---------- h_star = tanh(r@Wp + H[:, -1, :]@Wx) ----------
__global__ void k_hstar(const float* __restrict__ rbuf, const unsigned short* __restrict__ Hbf,
                        const float* __restrict__ Wp, const float* __restrict__ Wx,
                        float* __restrict__ hst) {
    __shared__ float sA[16][65];
    __shared__ float sB[16][65];
    int bn = blockIdx.x * 64, bm = blockIdx.y * 64;
    int tx = threadIdx.x & 15, ty = threadIdx.x >> 4;
    float acc[4][4] = {};
    for (int src = 0; src < 2; ++src) {
        const float* Bm = src ? Wx : Wp;
        for (int k0 = 0; k0 < DHz; k0 += 16) {
            for (int l = threadIdx.x; l < 64 * 16; l += 256) {
                int mm = l >> 4, kk = l & 15;
                sA[kk][mm] = src ? bf2f(Hbf[((long)(bm + mm) * Tz + (Tz - 1)) * DHz + k0 + kk])
                                 : rbuf[(long)(bm + mm) * DHz + k0 + kk];
            }
            for (int l = threadIdx.x; l < 16 * 64; l += 256) {
                int kk = l >> 6, nn = l & 63;
                sB[kk][nn] = Bm[(long)(k0 + kk) * DHz + bn + nn];
            }
            __syncthreads();
            for (int k = 0; k < 16; ++k) {
                float a0[4], b0[4];
#pragma unroll
                for (int i = 0; i < 4; ++i) a0[i] = sA[k][ty * 4 + i];
#pragma unroll
                for (int j = 0; j < 4; ++j) b0[j] = sB[k][tx * 4 + j];
#pragma unroll
                for (int i = 0; i < 4; ++i)
#pragma unroll
                    for (int j = 0; j < 4; ++j) acc[i][j] += a0[i] * b0[j];
            }
            __syncthreads();
        }
    }
#pragma unroll
    for (int i = 0; i < 4; ++i)
#pragma unroll
        for (int j = 0; j < 4; ++j)
            hst[(long)(bm + ty * 4 + i) * DHz + bn + tx * 4 + j] = tanhf(acc[i][j]);
}

// ---------- logits ----------
__global__ void k_logits(const float* __restrict__ hst, const float* __restrict__ Wl,
                         const float* __restrict__ bl, float* __restrict__ out) {
    int b = blockIdx.x;
    int lane = threadIdx.x & 63, c = threadIdx.x >> 6;
    float s = 0.f;
    for (int k = lane; k < DHz; k += 64) s += hst[(long)b * DHz + k] * Wl[k * 3 + c];
#pragma unroll
    for (int o = 32; o; o >>= 1) s += __shfl_xor(s, o, 64);
    if (lane == 0) out[b * 3 + c] = s + bl[c];
}

extern "C" void kernel_launch(void* const* d_in, const int* in_sizes, int n_in,
                              void* d_out, int out_size, void* d_ws, size_t ws_size,
                              hipStream_t stream) {
    (void)in_sizes; (void)n_in; (void)out_size; (void)ws_size;
    const int*   sent   = (const int*)d_in[0];
    const int*   target = (const int*)d_in[1];
    const int*   lens   = (const int*)d_in[2];
    const float* emb    = (const float*)d_in[3];
    const float* temb   = (const float*)d_in[4];
    const float* W_ih   = (const float*)d_in[5];
    const float* W_hh   = (const float*)d_in[6];
    const float* b_lstm = (const float*)d_in[7];
    const float* Wh     = (const float*)d_in[8];
    const float* wv     = (const float*)d_in[10];
    const float* Wp     = (const float*)d_in[11];
    const float* Wx     = (const float*)d_in[12];
    const float* W_lin  = (const float*)d_in[13];
    const float* b_lin  = (const float*)d_in[14];
    float* out = (float*)d_out;

    char* ws = (char*)d_ws;
    size_t off = 0;
    auto alloc = [&](size_t bytes) -> void* {
        void* p = ws + off;
        off = (off + bytes + 255) & ~(size_t)255;
        return p;
    };
    unsigned short* xW   = (unsigned short*)alloc((size_t)32768 * G4z * 2);
    unsigned short* Hbf  = (unsigned short*)alloc((size_t)Bz * Tz * DHz * 2);
    unsigned short* Wihb = (unsigned short*)alloc((size_t)DWz * G4z * 2);
    unsigned short* WhhP = (unsigned short*)alloc((size_t)48 * 6144 * 16);
    unsigned short* Whb  = (unsigned short*)alloc((size_t)DHz * DHz * 2);
    float* tx     = (float*)alloc((size_t)Bz * DWz * 4);
    float* constg = (float*)alloc((size_t)Bz * G4z * 4);
    float* cbuf   = (float*)alloc((size_t)Bz * DHz * 4);
    float* scores = (float*)alloc((size_t)Bz * Tz * 4);
    float* alpha  = (float*)alloc((size_t)Bz * Tz * 4);
    float* rbuf   = (float*)alloc((size_t)Bz * DHz * 4);
    float* hst    = (float*)alloc((size_t)Bz * DHz * 4);
    unsigned* bar = (unsigned*)alloc(256);

    k_cvt4<<<1024, 256, 0, stream>>>(W_ih, Wihb, DWz * G4z / 4);
    k_cvt4<<<512, 256, 0, stream>>>(Wh, Whb, DHz * DHz / 4);
    k_prep_whh<<<1152, 256, 0, stream>>>(W_hh, WhhP);
    k_prep_tx<<<Bz, 256, 0, stream>>>(target, temb, tx);
    hipMemsetAsync(scores, 0, (size_t)Bz * Tz * 4, stream);
    hipMemsetAsync(bar, 0, 256, stream);

    k_gemm_f32_bias<<<dim3(48, 4), 256, 0, stream>>>(tx, W_ih + (size_t)DWz * G4z, b_lstm,
                                                     constg, Bz, G4z, DWz, DWz, G4z);
    k_gemm_x<<<dim3(24, 256), 256, 0, stream>>>(emb, sent, Wihb, xW);

    // persistent LSTM under cooperative launch (co-residency guarantee), but with
    // a hand-rolled barrier instead of grid.sync()
    hipFuncSetAttribute((const void*)k_lstm_all,
                        hipFuncAttributeMaxDynamicSharedMemorySize, 98304);
    int t0v = 0, t1v = Tz;
    const unsigned short* xWp = xW;
    const float* cgp = constg;
    const unsigned short* whp = WhhP;
    unsigned short* hbp = Hbf;
    float* cbp = cbuf;
    const int* lnp = lens;
    unsigned* barp = bar;
    void* kargs[] = {&t0v, &t1v, &xWp, &cgp, &whp, &hbp, &cbp, &lnp, &barp};
    hipError_t ce = hipLaunchCooperativeKernel(reinterpret_cast<void*>(k_lstm_all),
                                               dim3(NBLK), dim3(256), kargs, 98304, stream);
    if (ce != hipSuccess) {
        for (int t = 0; t < Tz; ++t)
            k_lstm_all<<<NBLK, 256, 98304, stream>>>(t, t + 1, xW, constg, WhhP, Hbf, cbuf, lens, bar);
    }

    k_scores<<<dim3(6, 256), 256, 0, stream>>>(Hbf, Whb, wv, scores);
    k_softmax<<<Bz, 128, 0, stream>>>(scores, lens, alpha);
    k_r<<<Bz, 256, 0, stream>>>(alpha, Hbf, rbuf);
    k_hstar<<<dim3(12, 4), 256, 0, stream>>>(rbuf, Hbf, Wp, Wx, hst);
    k_logits<<<Bz, 192, 0, stream>>>(hst, W_lin, b_lin, out);
}

// Round 4
// 2858.622 us; speedup vs baseline: 1.9604x; 1.3466x over previous
//
#include <hip/hip_runtime.h>
#include <stdint.h>

#define Bz 256
#define Tz 128
#define DWz 768
#define DHz 768
#define G4z 3072
#define NBLK 96

typedef __attribute__((ext_vector_type(8))) short short8;
typedef __attribute__((ext_vector_type(4))) float f32x4;

__device__ __forceinline__ unsigned short f2bf(float x) {
    union { float f; unsigned int u; } v; v.f = x;
    unsigned int u = v.u;
    return (unsigned short)((u + 0x7fffu + ((u >> 16) & 1u)) >> 16);
}
__device__ __forceinline__ float bf2f(unsigned short h) {
    union { unsigned int u; float f; } v; v.u = ((unsigned int)h) << 16;
    return v.f;
}
__device__ __forceinline__ float sigm(float x) { return 1.0f / (1.0f + expf(-x)); }
__device__ __forceinline__ int sboff(int n, int k) {
    return n * 40 + ((((k >> 3) ^ ((n >> 3) & 3))) << 3) + (k & 7);
}

// ---------- fp32 -> bf16 bulk convert ----------
__global__ void k_cvt4(const float* __restrict__ src, unsigned short* __restrict__ dst, int n4) {
    int i = blockIdx.x * blockDim.x + threadIdx.x;
    int st = gridDim.x * blockDim.x;
    for (; i < n4; i += st) {
        float4 v = ((const float4*)src)[i];
        ushort4 o;
        o.x = f2bf(v.x); o.y = f2bf(v.y); o.z = f2bf(v.z); o.w = f2bf(v.w);
        ((ushort4*)dst)[i] = o;
    }
}

// ---------- gather aspect embedding ----------
__global__ void k_prep_tx(const int* __restrict__ target, const float* __restrict__ temb,
                          float* __restrict__ tx) {
    int b = blockIdx.x;
    long row = (long)target[b] * DWz;
    for (int d = threadIdx.x; d < DWz; d += blockDim.x)
        tx[b * DWz + d] = temb[row + d];
}

// ---------- Whh -> pre-swizzled bf16 blobs matching the persistent kernel's LDS layout ----
__global__ void k_prep_whh(const float* __restrict__ Whh, unsigned short* __restrict__ WhhP) {
    int id = blockIdx.x * 256 + threadIdx.x;   // [0, 48*6144)
    int dblk = id / 6144;
    int rem = id - dblk * 6144;
    int k0c = rem >> 8;
    int slot = rem & 255;
    int nl = slot >> 2, cc = slot & 3;
    int q8 = cc ^ ((nl >> 1) & 3);
    int k = k0c * 32 + q8 * 8;
    int col = (nl >> 4) * 768 + dblk * 16 + (nl & 15);
    alignas(16) unsigned short o[8];
#pragma unroll
    for (int e = 0; e < 8; ++e) o[e] = f2bf(Whh[(long)(k + e) * G4z + col]);
    *(int4*)(WhhP + (long)id * 8) = *(const int4*)o;
}

// ---------- generic fp32 tiled GEMM with bias (for const_gates) ----------
__global__ void k_gemm_f32_bias(const float* __restrict__ A, const float* __restrict__ Bm,
                                const float* __restrict__ bias, float* __restrict__ C,
                                int M, int N, int K, int lda, int ldb) {
    __shared__ float sA[16][65];
    __shared__ float sB[16][65];
    int bn = blockIdx.x * 64, bm = blockIdx.y * 64;
    int tx = threadIdx.x & 15, ty = threadIdx.x >> 4;
    float acc[4][4] = {};
    for (int k0 = 0; k0 < K; k0 += 16) {
        for (int l = threadIdx.x; l < 64 * 16; l += 256) {
            int m = l >> 4, k = l & 15;
            sA[k][m] = A[(long)(bm + m) * lda + k0 + k];
        }
        for (int l = threadIdx.x; l < 16 * 64; l += 256) {
            int k = l >> 6, n = l & 63;
            sB[k][n] = Bm[(long)(k0 + k) * ldb + bn + n];
        }
        __syncthreads();
        for (int k = 0; k < 16; ++k) {
            float a0[4], b0[4];
#pragma unroll
            for (int i = 0; i < 4; ++i) a0[i] = sA[k][ty * 4 + i];
#pragma unroll
            for (int j = 0; j < 4; ++j) b0[j] = sB[k][tx * 4 + j];
#pragma unroll
            for (int i = 0; i < 4; ++i)
#pragma unroll
                for (int j = 0; j < 4; ++j) acc[i][j] += a0[i] * b0[j];
        }
        __syncthreads();
    }
#pragma unroll
    for (int i = 0; i < 4; ++i)
#pragma unroll
        for (int j = 0; j < 4; ++j) {
            int m = bm + ty * 4 + i, n = bn + tx * 4 + j;
            C[(long)m * N + n] = acc[i][j] + bias[n];
        }
}

// ---------- xW = emb[sent] @ W_ih[:768]  (bf16 MFMA, row m' = t*256+b) ----------
__global__ __launch_bounds__(256) void k_gemm_x(const float* __restrict__ emb,
                                                const int* __restrict__ sent,
                                                const unsigned short* __restrict__ Wb,
                                                unsigned short* __restrict__ xW) {
    __shared__ unsigned short sA[128 * 40];
    __shared__ unsigned short sB[128 * 40];
    int tid = threadIdx.x;
    int n0 = blockIdx.x * 128;
    int m0 = blockIdx.y * 128;
    int wid = tid >> 6, lane = tid & 63, l15 = lane & 15, q = lane >> 4;
    int wm = wid >> 1, wn = wid & 1;

    int arow = tid >> 1;
    int kp = (tid & 1) * 16;
    int m = m0 + arow;
    int tt = m >> 8;
    int bb = m & 255;
    long gbase = (long)sent[bb * Tz + tt] * DWz;

    f32x4 acc[4][4];
    f32x4 zz = {0.f, 0.f, 0.f, 0.f};
#pragma unroll
    for (int i = 0; i < 4; ++i)
#pragma unroll
        for (int j = 0; j < 4; ++j) acc[i][j] = zz;

    for (int k0 = 0; k0 < DWz; k0 += 32) {
        {
            const float* src = emb + gbase + k0 + kp;
            alignas(16) unsigned short tmp[16];
#pragma unroll
            for (int it = 0; it < 4; ++it) {
                float4 v = ((const float4*)src)[it];
                tmp[it * 4 + 0] = f2bf(v.x); tmp[it * 4 + 1] = f2bf(v.y);
                tmp[it * 4 + 2] = f2bf(v.z); tmp[it * 4 + 3] = f2bf(v.w);
            }
            *(int4*)(sA + arow * 40 + kp) = *(const int4*)tmp;
            *(int4*)(sA + arow * 40 + kp + 8) = *(const int4*)(tmp + 8);
        }
#pragma unroll
        for (int it = 0; it < 2; ++it) {
            int s = tid + it * 256;
            int k = s >> 4;
            int n = (s & 15) * 8;
            int4 v = *(const int4*)(Wb + (long)(k0 + k) * G4z + n0 + n);
            const unsigned short* pv = (const unsigned short*)&v;
#pragma unroll
            for (int e = 0; e < 8; ++e) sB[sboff(n + e, k)] = pv[e];
        }
        __syncthreads();
        short8 af[4], bfr[4];
#pragma unroll
        for (int i = 0; i < 4; ++i)
            af[i] = *(const short8*)(sA + (wm * 64 + i * 16 + l15) * 40 + q * 8);
#pragma unroll
        for (int j = 0; j < 4; ++j) {
            int n = wn * 64 + j * 16 + l15;
            bfr[j] = *(const short8*)(sB + n * 40 + ((q ^ ((n >> 3) & 3)) << 3));
        }
#pragma unroll
        for (int i = 0; i < 4; ++i)
#pragma unroll
            for (int j = 0; j < 4; ++j)
                acc[i][j] = __builtin_amdgcn_mfma_f32_16x16x32_bf16(af[i], bfr[j], acc[i][j], 0, 0, 0);
        __syncthreads();
    }
#pragma unroll
    for (int i = 0; i < 4; ++i) {
        int row = m0 + wm * 64 + i * 16 + q * 4;
#pragma unroll
        for (int j = 0; j < 4; ++j) {
            int col = n0 + wn * 64 + j * 16 + l15;
#pragma unroll
            for (int r = 0; r < 4; ++r)
                xW[(long)(row + r) * G4z + col] = f2bf(acc[i][j][r]);
        }
    }
}

// ---------- persistent LSTM, fence-free ----------
// 96 blocks: bm = blockIdx&1 (128 batch rows), dblk = blockIdx>>1 (16 d's per gate).
// Whh slice (96KB) LDS-resident. h is exchanged via write-through system-scope
// stores (sc0 sc1 -> coherent at L3); reader A-loads are plain dwordx4 (each h(t)
// line is first-touched by a reader XCD only after the write-through). Barrier is
// per-bm-group (48 blocks), distributed arrive slots + leader go-flag, all relaxed
// system atomics -- no buffer_wbl2 / buffer_inv anywhere.
__global__ __launch_bounds__(256, 1) void k_lstm_all(int t0, int t1,
        const unsigned short* __restrict__ xW, const float* __restrict__ constg,
        const unsigned short* __restrict__ WhhP, unsigned short* __restrict__ Hbf,
        float* __restrict__ cbuf, const int* __restrict__ lens,
        unsigned* __restrict__ bar) {
    extern __shared__ unsigned short sB[];   // 96 KB
    int tid = threadIdx.x;
    int bm = blockIdx.x & 1;
    int dblk = blockIdx.x >> 1;
    int d0 = dblk * 16;
    int lane = tid & 63, wid = tid >> 6;
    int l15 = lane & 15, q = lane >> 4;
    int d = d0 + l15;

    {   // stage pre-swizzled B once
        const int4* src = (const int4*)WhhP + (long)dblk * 6144;
        for (int s = tid; s < 6144; s += 256) ((int4*)sB)[s] = src[s];
    }

    int brow[8];
    int lenr[8];
    float c[8], h[8];
    float xgc[2][4][4];   // step-invariant gate constants, register-resident
#pragma unroll
    for (int i = 0; i < 2; ++i)
#pragma unroll
        for (int r = 0; r < 4; ++r) {
            int ir = i * 4 + r;
            int b = bm * 128 + wid * 32 + i * 16 + q * 4 + r;
            brow[ir] = b;
            lenr[ir] = lens[b];
            long cbase = (long)b * G4z + d;
#pragma unroll
            for (int j = 0; j < 4; ++j) xgc[i][j][r] = constg[cbase + j * 768];
            if (t0 > 0) {
                c[ir] = cbuf[(long)b * DHz + d];
                h[ir] = bf2f(Hbf[((long)b * Tz + (t0 - 1)) * DHz + d]);
            } else { c[ir] = 0.f; h[ir] = 0.f; }
        }

    int bbase[4];
#pragma unroll
    for (int j = 0; j < 4; ++j) {
        int nl = j * 16 + l15;
        bbase[j] = nl * 32 + ((q ^ ((nl >> 1) & 3)) << 3);
    }
    __syncthreads();

    // gate x-contributions for step t0
    float xg[2][4][4];
#pragma unroll
    for (int i = 0; i < 2; ++i)
#pragma unroll
        for (int r = 0; r < 4; ++r) {
            int ir = i * 4 + r;
            long xbase = ((long)t0 * 256 + brow[ir]) * G4z + d;
#pragma unroll
            for (int j = 0; j < 4; ++j)
                xg[i][j][r] = bf2f(xW[xbase + j * 768]) + xgc[i][j][r];
        }

    for (int t = t0; t < t1; ++t) {
        f32x4 acc[2][4];
        f32x4 zz = {0.f, 0.f, 0.f, 0.f};
#pragma unroll
        for (int i = 0; i < 2; ++i)
#pragma unroll
            for (int j = 0; j < 4; ++j) acc[i][j] = zz;

        if (t > 0) {
            const unsigned short* ap0 = Hbf + ((long)(bm * 128 + wid * 32 + l15) * Tz + (t - 1)) * DHz + q * 8;
            const unsigned short* ap1 = ap0 + (long)16 * Tz * DHz;
#pragma unroll 6
            for (int k0c = 0; k0c < 24; ++k0c) {
                short8 a0 = *(const short8*)(ap0 + k0c * 32);
                short8 a1 = *(const short8*)(ap1 + k0c * 32);
                const unsigned short* bb = sB + k0c * 2048;
#pragma unroll
                for (int j = 0; j < 4; ++j) {
                    short8 bf = *(const short8*)(bb + bbase[j]);
                    acc[0][j] = __builtin_amdgcn_mfma_f32_16x16x32_bf16(a0, bf, acc[0][j], 0, 0, 0);
                    acc[1][j] = __builtin_amdgcn_mfma_f32_16x16x32_bf16(a1, bf, acc[1][j], 0, 0, 0);
                }
            }
        }

        // in-register gate pointwise; h stored write-through (system scope)
#pragma unroll
        for (int i = 0; i < 2; ++i)
#pragma unroll
            for (int r = 0; r < 4; ++r) {
                int ir = i * 4 + r;
                float gi = acc[i][0][r] + xg[i][0][r];
                float gf = acc[i][1][r] + xg[i][1][r];
                float gg = acc[i][2][r] + xg[i][2][r];
                float go = acc[i][3][r] + xg[i][3][r];
                float cn = sigm(gf) * c[ir] + sigm(gi) * tanhf(gg);
                float hn = sigm(go) * tanhf(cn);
                bool upd = t < lenr[ir];
                c[ir] = upd ? cn : c[ir];
                h[ir] = upd ? hn : h[ir];
                __hip_atomic_store(Hbf + ((long)brow[ir] * Tz + t) * DHz + d, f2bf(h[ir]),
                                   __ATOMIC_RELAXED, __HIP_MEMORY_SCOPE_SYSTEM);
            }

        if (t + 1 < t1) {
            // prefetch next step's xW before the barrier (overlaps spin)
            unsigned short xwn[2][4][4];
#pragma unroll
            for (int i = 0; i < 2; ++i)
#pragma unroll
                for (int r = 0; r < 4; ++r) {
                    int ir = i * 4 + r;
                    long xbase = ((long)(t + 1) * 256 + brow[ir]) * G4z + d;
#pragma unroll
                    for (int j = 0; j < 4; ++j) xwn[i][j][r] = xW[xbase + j * 768];
                }

            __syncthreads();   // vmcnt(0): h write-through stores acked at coherent point
            unsigned tgt = (unsigned)(t - t0 + 1);
            if (tid == 0)
                __hip_atomic_store(&bar[(bm * 48 + dblk) * 32], tgt,
                                   __ATOMIC_RELAXED, __HIP_MEMORY_SCOPE_SYSTEM);
            if (dblk == 0) {       // group leader: gather 48 arrivals, publish go
                if (tid < 48) {
                    while (__hip_atomic_load(&bar[(bm * 48 + tid) * 32],
                                             __ATOMIC_RELAXED, __HIP_MEMORY_SCOPE_SYSTEM) < tgt)
                        __builtin_amdgcn_s_sleep(1);
                }
                __syncthreads();
                if (tid == 0)
                    __hip_atomic_store(&bar[(96 + bm) * 32], tgt,
                                       __ATOMIC_RELAXED, __HIP_MEMORY_SCOPE_SYSTEM);
            } else {
                if (tid == 0) {
                    while (__hip_atomic_load(&bar[(96 + bm) * 32],
                                             __ATOMIC_RELAXED, __HIP_MEMORY_SCOPE_SYSTEM) < tgt)
                        __builtin_amdgcn_s_sleep(1);
                }
                __syncthreads();
            }
            asm volatile("" ::: "memory");   // no hoisting of A-loads above the spin

#pragma unroll
            for (int i = 0; i < 2; ++i)
#pragma unroll
                for (int j = 0; j < 4; ++j)
#pragma unroll
                    for (int r = 0; r < 4; ++r)
                        xg[i][j][r] = bf2f(xwn[i][j][r]) + xgc[i][j][r];
        }
    }
#pragma unroll
    for (int ir = 0; ir < 8; ++ir) cbuf[(long)brow[ir] * DHz + d] = c[ir];
}

// ---------- scores[b,t] = sum_d w[d]*tanh( (H@Wh)[b,t,d] ) ----------
__global__ __launch_bounds__(256) void k_scores(const unsigned short* __restrict__ Hbf,
                                                const unsigned short* __restrict__ Whb,
                                                const float* __restrict__ wv,
                                                float* __restrict__ scores) {
    __shared__ unsigned short sA[128 * 40];
    __shared__ unsigned short sB[128 * 40];
    __shared__ float sred[128];
    int tid = threadIdx.x;
    int n0 = blockIdx.x * 128;
    int m0 = blockIdx.y * 128;
    int wid = tid >> 6, lane = tid & 63, l15 = lane & 15, q = lane >> 4;
    int wm = wid >> 1, wn = wid & 1;

    f32x4 acc[4][4];
    f32x4 zz = {0.f, 0.f, 0.f, 0.f};
#pragma unroll
    for (int i = 0; i < 4; ++i)
#pragma unroll
        for (int j = 0; j < 4; ++j) acc[i][j] = zz;

    int arow = tid >> 1;
    int kp = (tid & 1) * 16;
    const unsigned short* asrc = Hbf + (long)(m0 + arow) * DHz;

    for (int k0 = 0; k0 < DHz; k0 += 32) {
        *(int4*)(sA + arow * 40 + kp) = *(const int4*)(asrc + k0 + kp);
        *(int4*)(sA + arow * 40 + kp + 8) = *(const int4*)(asrc + k0 + kp + 8);
#pragma unroll
        for (int it = 0; it < 2; ++it) {
            int s = tid + it * 256;
            int k = s >> 4;
            int n = (s & 15) * 8;
            int4 v = *(const int4*)(Whb + (long)(k0 + k) * DHz + n0 + n);
            const unsigned short* pv = (const unsigned short*)&v;
#pragma unroll
            for (int e = 0; e < 8; ++e) sB[sboff(n + e, k)] = pv[e];
        }
        __syncthreads();
        short8 af[4], bfr[4];
#pragma unroll
        for (int i = 0; i < 4; ++i)
            af[i] = *(const short8*)(sA + (wm * 64 + i * 16 + l15) * 40 + q * 8);
#pragma unroll
        for (int j = 0; j < 4; ++j) {
            int n = wn * 64 + j * 16 + l15;
            bfr[j] = *(const short8*)(sB + n * 40 + ((q ^ ((n >> 3) & 3)) << 3));
        }
#pragma unroll
        for (int i = 0; i < 4; ++i)
#pragma unroll
            for (int j = 0; j < 4; ++j)
                acc[i][j] = __builtin_amdgcn_mfma_f32_16x16x32_bf16(af[i], bfr[j], acc[i][j], 0, 0, 0);
        __syncthreads();
    }
    if (tid < 128) sred[tid] = 0.f;
    __syncthreads();
#pragma unroll
    for (int i = 0; i < 4; ++i)
#pragma unroll
        for (int r = 0; r < 4; ++r) {
            float sv = 0.f;
#pragma unroll
            for (int j = 0; j < 4; ++j) {
                int n = n0 + wn * 64 + j * 16 + l15;
                sv += tanhf(acc[i][j][r]) * wv[n];
            }
#pragma unroll
            for (int o = 1; o < 16; o <<= 1) sv += __shfl_xor(sv, o, 64);
            if (l15 == 0) atomicAdd(&sred[wm * 64 + i * 16 + q * 4 + r], sv);
        }
    __syncthreads();
    if (tid < 128) atomicAdd(&scores[m0 + tid], sred[tid]);
}

// ---------- masked softmax over T ----------
__global__ void k_softmax(const float* __restrict__ scores, const int* __restrict__ lens,
                          float* __restrict__ alpha) {
    int b = blockIdx.x, t = threadIdx.x;
    int len = lens[b];
    float s = (t < len) ? scores[b * Tz + t] : -1e9f;
    float m = s;
#pragma unroll
    for (int o = 32; o; o >>= 1) m = fmaxf(m, __shfl_xor(m, o, 64));
    __shared__ float rA[2], rB[2];
    if ((t & 63) == 0) rA[t >> 6] = m;
    __syncthreads();
    m = fmaxf(rA[0], rA[1]);
    float e = expf(s - m);
    float sum = e;
#pragma unroll
    for (int o = 32; o; o >>= 1) sum += __shfl_xor(sum, o, 64);
    if ((t & 63) == 0) rB[t >> 6] = sum;
    __syncthreads();
    sum = rB[0] + rB[1];
    alpha[b * Tz + t] = e / sum;
}

// ---------- r[b,d] = sum_t alpha[b,t] * H[b,t,d] ----------
__global__ void k_r(const float* __restrict__ alpha, const unsigned short* __restrict__ Hbf,
                    float* __restrict__ rbuf) {
    int b = blockIdx.x;
    __shared__ float sal[Tz];
    if (threadIdx.x < Tz) sal[threadIdx.x] = alpha[b * Tz + threadIdx.x];
    __syncthreads();
    for (int d = threadIdx.x; d < DHz; d += blockDim.x) {
        float acc = 0.f;
        for (int t = 0; t < Tz; ++t) acc += sal[t] * bf2f(Hbf[((long)b * Tz + t) * DHz + d]);
        rbuf[(long)b * DHz + d] = acc;
    }
}

// ---------- h_star = tanh(r@Wp + H[:, -1, :]@Wx) ----------
__global__ void k_hstar(const float* __restrict__ rbuf, const unsigned short* __restrict__ Hbf,
                        const float* __restrict__ Wp, const float* __restrict__ Wx,
                        float* __restrict__ hst) {
    __shared__ float sA[16][65];
    __shared__ float sB[16][65];
    int bn = blockIdx.x * 64, bm = blockIdx.y * 64;
    int tx = threadIdx.x & 15, ty = threadIdx.x >> 4;
    float acc[4][4] = {};
    for (int src = 0; src < 2; ++src) {
        const float* Bm = src ? Wx : Wp;
        for (int k0 = 0; k0 < DHz; k0 += 16) {
            for (int l = threadIdx.x; l < 64 * 16; l += 256) {
                int mm = l >> 4, kk = l & 15;
                sA[kk][mm] = src ? bf2f(Hbf[((long)(bm + mm) * Tz + (Tz - 1)) * DHz + k0 + kk])
                                 : rbuf[(long)(bm + mm) * DHz + k0 + kk];
            }
            for (int l = threadIdx.x; l < 16 * 64; l += 256) {
                int kk = l >> 6, nn = l & 63;
                sB[kk][nn] = Bm[(long)(k0 + kk) * DHz + bn + nn];
            }
            __syncthreads();
            for (int k = 0; k < 16; ++k) {
                float a0[4], b0[4];
#pragma unroll
                for (int i = 0; i < 4; ++i) a0[i] = sA[k][ty * 4 + i];
#pragma unroll
                for (int j = 0; j < 4; ++j) b0[j] = sB[k][tx * 4 + j];
#pragma unroll
                for (int i = 0; i < 4; ++i)
#pragma unroll
                    for (int j = 0; j < 4; ++j) acc[i][j] += a0[i] * b0[j];
            }
            __syncthreads();
        }
    }
#pragma unroll
    for (int i = 0; i < 4; ++i)
#pragma unroll
        for (int j = 0; j < 4; ++j)
            hst[(long)(bm + ty * 4 + i) * DHz + bn + tx * 4 + j] = tanhf(acc[i][j]);
}

// ---------- logits ----------
__global__ void k_logits(const float* __restrict__ hst, const float* __restrict__ Wl,
                         const float* __restrict__ bl, float* __restrict__ out) {
    int b = blockIdx.x;
    int lane = threadIdx.x & 63, c = threadIdx.x >> 6;
    float s = 0.f;
    for (int k = lane; k < DHz; k += 64) s += hst[(long)b * DHz + k] * Wl[k * 3 + c];
#pragma unroll
    for (int o = 32; o; o >>= 1) s += __shfl_xor(s, o, 64);
    if (lane == 0) out[b * 3 + c] = s + bl[c];
}

extern "C" void kernel_launch(void* const* d_in, const int* in_sizes, int n_in,
                              void* d_out, int out_size, void* d_ws, size_t ws_size,
                              hipStream_t stream) {
    (void)in_sizes; (void)n_in; (void)out_size; (void)ws_size;
    const int*   sent   = (const int*)d_in[0];
    const int*   target = (const int*)d_in[1];
    const int*   lens   = (const int*)d_in[2];
    const float* emb    = (const float*)d_in[3];
    const float* temb   = (const float*)d_in[4];
    const float* W_ih   = (const float*)d_in[5];
    const float* W_hh   = (const float*)d_in[6];
    const float* b_lstm = (const float*)d_in[7];
    const float* Wh     = (const float*)d_in[8];
    const float* wv     = (const float*)d_in[10];
    const float* Wp     = (const float*)d_in[11];
    const float* Wx     = (const float*)d_in[12];
    const float* W_lin  = (const float*)d_in[13];
    const float* b_lin  = (const float*)d_in[14];
    float* out = (float*)d_out;

    char* ws = (char*)d_ws;
    size_t off = 0;
    auto alloc = [&](size_t bytes) -> void* {
        void* p = ws + off;
        off = (off + bytes + 255) & ~(size_t)255;
        return p;
    };
    unsigned short* xW   = (unsigned short*)alloc((size_t)32768 * G4z * 2);
    unsigned short* Hbf  = (unsigned short*)alloc((size_t)Bz * Tz * DHz * 2);
    unsigned short* Wihb = (unsigned short*)alloc((size_t)DWz * G4z * 2);
    unsigned short* WhhP = (unsigned short*)alloc((size_t)48 * 6144 * 16);
    unsigned short* Whb  = (unsigned short*)alloc((size_t)DHz * DHz * 2);
    float* tx     = (float*)alloc((size_t)Bz * DWz * 4);
    float* constg = (float*)alloc((size_t)Bz * G4z * 4);
    float* cbuf   = (float*)alloc((size_t)Bz * DHz * 4);
    float* scores = (float*)alloc((size_t)Bz * Tz * 4);
    float* alpha  = (float*)alloc((size_t)Bz * Tz * 4);
    float* rbuf   = (float*)alloc((size_t)Bz * DHz * 4);
    float* hst    = (float*)alloc((size_t)Bz * DHz * 4);
    unsigned* bar = (unsigned*)alloc(16384);   // 96 arrive slots + 2 go flags, 128B apart

    k_cvt4<<<1024, 256, 0, stream>>>(W_ih, Wihb, DWz * G4z / 4);
    k_cvt4<<<512, 256, 0, stream>>>(Wh, Whb, DHz * DHz / 4);
    k_prep_whh<<<1152, 256, 0, stream>>>(W_hh, WhhP);
    k_prep_tx<<<Bz, 256, 0, stream>>>(target, temb, tx);
    hipMemsetAsync(scores, 0, (size_t)Bz * Tz * 4, stream);
    hipMemsetAsync(bar, 0, 16384, stream);

    k_gemm_f32_bias<<<dim3(48, 4), 256, 0, stream>>>(tx, W_ih + (size_t)DWz * G4z, b_lstm,
                                                     constg, Bz, G4z, DWz, DWz, G4z);
    k_gemm_x<<<dim3(24, 256), 256, 0, stream>>>(emb, sent, Wihb, xW);

    hipFuncSetAttribute((const void*)k_lstm_all,
                        hipFuncAttributeMaxDynamicSharedMemorySize, 98304);
    int t0v = 0, t1v = Tz;
    const unsigned short* xWp = xW;
    const float* cgp = constg;
    const unsigned short* whp = WhhP;
    unsigned short* hbp = Hbf;
    float* cbp = cbuf;
    const int* lnp = lens;
    unsigned* barp = bar;
    void* kargs[] = {&t0v, &t1v, &xWp, &cgp, &whp, &hbp, &cbp, &lnp, &barp};
    hipError_t ce = hipLaunchCooperativeKernel(reinterpret_cast<void*>(k_lstm_all),
                                               dim3(NBLK), dim3(256), kargs, 98304, stream);
    if (ce != hipSuccess) {
        for (int t = 0; t < Tz; ++t)
            k_lstm_all<<<NBLK, 256, 98304, stream>>>(t, t + 1, xW, constg, WhhP, Hbf, cbuf, lens, bar);
    }

    k_scores<<<dim3(6, 256), 256, 0, stream>>>(Hbf, Whb, wv, scores);
    k_softmax<<<Bz, 128, 0, stream>>>(scores, lens, alpha);
    k_r<<<Bz, 256, 0, stream>>>(alpha, Hbf, rbuf);
    k_hstar<<<dim3(12, 4), 256, 0, stream>>>(rbuf, Hbf, Wp, Wx, hst);
    k_logits<<<Bz, 192, 0, stream>>>(hst, W_lin, b_lin, out);
}